// Round 7
// baseline (617.566 us; speedup 1.0000x reference)
//
#include <hip/hip_runtime.h>
#include <math.h>

#define B_ 32
#define N_ 4096
#define D_ 64
#define T_ 12
#define EPS_ 1e-7f
#define PSTR 65

typedef float4 f4;
#define LD4(p) (*(const float4*)(p))

typedef __attribute__((ext_vector_type(8))) short short8;
typedef __attribute__((ext_vector_type(4))) short s4b;
typedef __attribute__((ext_vector_type(4))) float f32x4;
#define MFMA(a, b, c)   __builtin_amdgcn_mfma_f32_16x16x32_bf16(a, b, c, 0, 0, 0)
#define MFMA16(a, b, c) __builtin_amdgcn_mfma_f32_16x16x16bf16_1k(a, b, c, 0, 0, 0)

__device__ __forceinline__ float f4c(const float4 v, int q) {
    return q == 0 ? v.x : q == 1 ? v.y : q == 2 ? v.z : v.w;
}
__device__ __forceinline__ void fma8(float (&acc)[8], float a, const float4 w0, const float4 w1) {
    acc[0] = fmaf(a, w0.x, acc[0]); acc[1] = fmaf(a, w0.y, acc[1]);
    acc[2] = fmaf(a, w0.z, acc[2]); acc[3] = fmaf(a, w0.w, acc[3]);
    acc[4] = fmaf(a, w1.x, acc[4]); acc[5] = fmaf(a, w1.y, acc[5]);
    acc[6] = fmaf(a, w1.z, acc[6]); acc[7] = fmaf(a, w1.w, acc[7]);
}

// split fp32 -> bf16 hi (truncate) + bf16 lo (truncated remainder)
__device__ __forceinline__ void splitbf(float a, short& h, short& l) {
    unsigned x = __float_as_uint(a);
    h = (short)(x >> 16);
    float r = a - __uint_as_float(x & 0xffff0000u);
    l = (short)(__float_as_uint(r) >> 16);
}
// packed u32: low16 = hi-bf16, high16 = lo-bf16
__device__ __forceinline__ unsigned packsplit(float a) {
    unsigned x = __float_as_uint(a);
    unsigned hib = x & 0xffff0000u;
    float r = a - __uint_as_float(hib);
    return (x >> 16) | (__float_as_uint(r) & 0xffff0000u);
}
__device__ __forceinline__ float unpackf(unsigned p) {
    return __uint_as_float(p << 16) + __uint_as_float(p & 0xffff0000u);
}

// ---------------------------------------------------------------------------
// Prep: pack weights into MFMA fragment order (hi/lo planes) + bn contrib.
// w1 packs serve BOTH as B-frags (n=l&15) and W^T A-frags (m=l&15) — same map.
// New: W2^T packs in 16x16x16 A-layout (k = (l>>4)*4+e, m = mt2*16+(l&15)).
// ---------------------------------------------------------------------------
__global__ void prep_kernel(
    const float* __restrict__ cn_w1, const float* __restrict__ cn_w2,
    const float* __restrict__ bn_w1, const float* __restrict__ bn_w2,
    const float* __restrict__ bn_b1, const float* __restrict__ label_emb,
    short* __restrict__ p_cn1h, short* __restrict__ p_cn1l,
    short* __restrict__ p_bn1h, short* __restrict__ p_bn1l,
    short* __restrict__ p_cn2h, short* __restrict__ p_cn2l,
    short* __restrict__ p_bn2h, short* __restrict__ p_bn2l,
    short* __restrict__ p_c2th, short* __restrict__ p_c2tl,
    short* __restrict__ p_b2th, short* __restrict__ p_b2tl,
    float* __restrict__ contrib)
{
    const int tid = threadIdx.x;
    for (int idx = tid; idx < 8192; idx += 256) {   // w1 packs (K=128)
        const int e = idx & 7, l = (idx >> 3) & 63, fb = idx >> 9;
        const int kt = fb >> 2, nt = fb & 3;
        const int k = kt * 32 + (l >> 4) * 8 + e;
        const int n = nt * 16 + (l & 15);
        short h, lo;
        splitbf(cn_w1[k * 64 + n], h, lo); p_cn1h[idx] = h; p_cn1l[idx] = lo;
        splitbf(bn_w1[k * 64 + n], h, lo); p_bn1h[idx] = h; p_bn1l[idx] = lo;
    }
    for (int idx = tid; idx < 4096; idx += 256) {   // w2 packs (K=64, 16x16x32 B)
        const int e = idx & 7, l = (idx >> 3) & 63, fb = idx >> 9;
        const int kt = fb >> 2, nt = fb & 3;
        const int k = kt * 32 + (l >> 4) * 8 + e;
        const int n = nt * 16 + (l & 15);
        short h, lo;
        splitbf(cn_w2[k * 64 + n], h, lo); p_cn2h[idx] = h; p_cn2l[idx] = lo;
        splitbf(bn_w2[k * 64 + n], h, lo); p_bn2h[idx] = h; p_bn2l[idx] = lo;
    }
    for (int idx = tid; idx < 4096; idx += 256) {   // w2^T packs (16x16x16 A)
        const int e = idx & 3, l = (idx >> 2) & 63, fb = idx >> 8;
        const int ks = fb >> 2, mt2 = fb & 3;
        const int k = ks * 16 + (l >> 4) * 4 + e;
        const int n = mt2 * 16 + (l & 15);
        short h, lo;
        splitbf(cn_w2[k * 64 + n], h, lo); p_c2th[idx] = h; p_c2tl[idx] = lo;
        splitbf(bn_w2[k * 64 + n], h, lo); p_b2th[idx] = h; p_b2tl[idx] = lo;
    }
    if (tid < 128) {                                 // contrib[c][n] = b1[n] + le[c]@bn_w1[128:]
        const int c = tid >> 6, n = tid & 63;
        float s = bn_b1[n];
        for (int kk = 0; kk < 64; ++kk)
            s = fmaf(label_emb[c * 64 + kk], bn_w1[(128 + kk) * 64 + n], s);
        contrib[c * 64 + n] = s;
    }
}

// ---------------------------------------------------------------------------
// Embedding (fp32 vector; small). Writes e as bf16 hi/lo planes.
// ---------------------------------------------------------------------------
__global__ __launch_bounds__(256, 4) void emb_kernel(
    const int* __restrict__ x, const float* __restrict__ y,
    const float* __restrict__ w1, const float* __restrict__ b1,
    const float* __restrict__ w2, const float* __restrict__ b2,
    short* __restrict__ e_hi, short* __restrict__ e_lo, int* __restrict__ v_out)
{
    __shared__ float h_lds[128 * PSTR];
    const int tid = threadIdx.x;
    const int s   = tid & 7;
    const int g   = tid >> 3;
    const int jj0 = s * 8;
    const int i0  = (blockIdx.x * 32 + g) * 4;

    {
        f4 wa0 = LD4(w1 + jj0),      wa1 = LD4(w1 + jj0 + 4);
        f4 wb0 = LD4(w1 + D_ + jj0), wb1 = LD4(w1 + D_ + jj0 + 4);
        f4 bb0 = LD4(b1 + jj0),      bb1 = LD4(b1 + jj0 + 4);
#pragma unroll
        for (int pp = 0; pp < 4; ++pp) {
            const float2 yv = *(const float2*)(y + 2 * (i0 + pp));
            f4 h0, h1;
            h0.x = fmaxf(fmaf(yv.y, wb0.x, fmaf(yv.x, wa0.x, bb0.x)), 0.f);
            h0.y = fmaxf(fmaf(yv.y, wb0.y, fmaf(yv.x, wa0.y, bb0.y)), 0.f);
            h0.z = fmaxf(fmaf(yv.y, wb0.z, fmaf(yv.x, wa0.z, bb0.z)), 0.f);
            h0.w = fmaxf(fmaf(yv.y, wb0.w, fmaf(yv.x, wa0.w, bb0.w)), 0.f);
            h1.x = fmaxf(fmaf(yv.y, wb1.x, fmaf(yv.x, wa1.x, bb1.x)), 0.f);
            h1.y = fmaxf(fmaf(yv.y, wb1.y, fmaf(yv.x, wa1.y, bb1.y)), 0.f);
            h1.z = fmaxf(fmaf(yv.y, wb1.z, fmaf(yv.x, wa1.z, bb1.z)), 0.f);
            h1.w = fmaxf(fmaf(yv.y, wb1.w, fmaf(yv.x, wa1.w, bb1.w)), 0.f);
            float* hp = h_lds + (g * 4 + pp) * PSTR + jj0;
            *(f4*)hp = h0; *(f4*)(hp + 4) = h1;
        }
    }
    __syncthreads();

    float o[4][8];
    {
        f4 b20 = LD4(b2 + jj0), b21 = LD4(b2 + jj0 + 4);
#pragma unroll
        for (int pp = 0; pp < 4; ++pp) {
            o[pp][0]=b20.x; o[pp][1]=b20.y; o[pp][2]=b20.z; o[pp][3]=b20.w;
            o[pp][4]=b21.x; o[pp][5]=b21.y; o[pp][6]=b21.z; o[pp][7]=b21.w;
        }
    }
#pragma unroll 2
    for (int k4 = 0; k4 < 16; ++k4) {
        const f4 x0 = LD4(h_lds + (g * 4 + 0) * PSTR + 4 * k4);
        const f4 x1 = LD4(h_lds + (g * 4 + 1) * PSTR + 4 * k4);
        const f4 x2 = LD4(h_lds + (g * 4 + 2) * PSTR + 4 * k4);
        const f4 x3 = LD4(h_lds + (g * 4 + 3) * PSTR + 4 * k4);
        const float* wk = w2 + (4 * k4) * D_ + jj0;
#pragma unroll
        for (int q = 0; q < 4; ++q) {
            const f4 wa = LD4(wk + q * D_), wb = LD4(wk + q * D_ + 4);
            fma8(o[0], f4c(x0, q), wa, wb);
            fma8(o[1], f4c(x1, q), wa, wb);
            fma8(o[2], f4c(x2, q), wa, wb);
            fma8(o[3], f4c(x3, q), wa, wb);
        }
    }

#pragma unroll
    for (int pp = 0; pp < 4; ++pp) {
        const size_t base = (size_t)(i0 + pp) * D_ + jj0;
        union { short s[8]; uint4 v; } uh, ul;
#pragma unroll
        for (int q = 0; q < 8; ++q) splitbf(o[pp][q], uh.s[q], ul.s[q]);
        *(uint4*)(e_hi + base) = uh.v;
        *(uint4*)(e_lo + base) = ul.v;
    }
    if (s < 4) v_out[i0 + s] = x[i0 + s];
}

// ---------------------------------------------------------------------------
// Global tree stage (used for t = 0,1,2). Round-6 proven kernel.
// ---------------------------------------------------------------------------
__global__ __launch_bounds__(256, 2) void pair_mfma(
    const short* __restrict__ e_hi, const short* __restrict__ e_lo,
    const int* __restrict__ v_in,
    short* __restrict__ eo_hi, short* __restrict__ eo_lo, int* __restrict__ v_out,
    const short* __restrict__ p_cn1h, const short* __restrict__ p_cn1l,
    const short* __restrict__ p_bn1h, const short* __restrict__ p_bn1l,
    const short* __restrict__ p_cn2h, const short* __restrict__ p_cn2l,
    const short* __restrict__ p_bn2h, const short* __restrict__ p_bn2l,
    const float* __restrict__ cn_b1, const float* __restrict__ cn_b2,
    const float* __restrict__ bn_b2, const float* __restrict__ contrib,
    const float* __restrict__ llr_w, const float* __restrict__ llr_b,
    float* __restrict__ loss_out, float* __restrict__ pred1, float* __restrict__ pred2,
    int t, int log2Lh)
{
    __shared__ unsigned int lds[4][2][32][68];
    const int tid  = threadIdx.x;
    const int wid  = tid >> 6, lane = tid & 63;
    const int rowm = lane & 15, kg = lane >> 4;
    const int P0   = (blockIdx.x * 4 + wid) * 32;
    const int b    = P0 >> 11;

    int vxm[2][4];
#pragma unroll
    for (int s = 0; s < 2; ++s)
#pragma unroll
        for (int r = 0; r < 4; ++r) {
            const int2 vv = *(const int2*)(v_in + 2 * (P0 + s * 16 + kg * 4 + r));
            vxm[s][r] = (vv.x ^ vv.y) & 1;
        }

    f32x4 aC[2][4], aB[2][4];
#pragma unroll
    for (int nt = 0; nt < 4; ++nt) {
        const float bc = cn_b1[nt * 16 + rowm];
#pragma unroll
        for (int s = 0; s < 2; ++s) {
            aC[s][nt] = (f32x4){bc, bc, bc, bc};
            f32x4 ab;
#pragma unroll
            for (int r = 0; r < 4; ++r) ab[r] = contrib[vxm[s][r] * 64 + nt * 16 + rowm];
            aB[s][nt] = ab;
        }
    }

#pragma unroll
    for (int kt = 0; kt < 4; ++kt) {
        short8 Ah[2], Al[2];
#pragma unroll
        for (int s = 0; s < 2; ++s) {
            const size_t pos = (size_t)(2 * (P0 + s * 16 + rowm) + (kt >> 1));
            const int off = (kt & 1) * 32 + kg * 8;
            Ah[s] = *(const short8*)(e_hi + pos * D_ + off);
            Al[s] = *(const short8*)(e_lo + pos * D_ + off);
        }
#pragma unroll
        for (int nt = 0; nt < 4; ++nt) {
            const int fo = ((kt * 4 + nt) * 64 + lane) * 8;
            const short8 bh = *(const short8*)(p_cn1h + fo);
            const short8 bl = *(const short8*)(p_cn1l + fo);
            const short8 ch = *(const short8*)(p_bn1h + fo);
            const short8 cl = *(const short8*)(p_bn1l + fo);
#pragma unroll
            for (int s = 0; s < 2; ++s) {
                aC[s][nt] = MFMA(Ah[s], bh, aC[s][nt]);
                aC[s][nt] = MFMA(Al[s], bh, aC[s][nt]);
                aC[s][nt] = MFMA(Ah[s], bl, aC[s][nt]);
                aB[s][nt] = MFMA(Ah[s], ch, aB[s][nt]);
                aB[s][nt] = MFMA(Al[s], ch, aB[s][nt]);
                aB[s][nt] = MFMA(Ah[s], cl, aB[s][nt]);
            }
        }
    }

#pragma unroll
    for (int s = 0; s < 2; ++s)
#pragma unroll
        for (int nt = 0; nt < 4; ++nt)
#pragma unroll
            for (int r = 0; r < 4; ++r) {
                lds[wid][0][s * 16 + kg * 4 + r][nt * 16 + rowm] = packsplit(fmaxf(aC[s][nt][r], 0.f));
                lds[wid][1][s * 16 + kg * 4 + r][nt * 16 + rowm] = packsplit(fmaxf(aB[s][nt][r], 0.f));
            }
    __builtin_amdgcn_wave_barrier();

#pragma unroll
    for (int net = 0; net < 2; ++net) {
        const short* __restrict__ w2h = net ? p_bn2h : p_cn2h;
        const short* __restrict__ w2l = net ? p_bn2l : p_cn2l;
        const float* __restrict__ b2  = net ? bn_b2 : cn_b2;

        f32x4 o[2][4];
#pragma unroll
        for (int nt = 0; nt < 4; ++nt) {
            const float bb = b2[nt * 16 + rowm];
#pragma unroll
            for (int s = 0; s < 2; ++s) o[s][nt] = (f32x4){bb, bb, bb, bb};
        }

#pragma unroll
        for (int kt = 0; kt < 2; ++kt) {
            short8 ah[2], al[2];
#pragma unroll
            for (int s = 0; s < 2; ++s) {
                unsigned xa[8];
#pragma unroll
                for (int e2 = 0; e2 < 8; ++e2)
                    xa[e2] = lds[wid][net][s * 16 + rowm][kt * 32 + kg * 8 + e2];
                union { short8 sv; unsigned u[4]; } th, tl;
#pragma unroll
                for (int j = 0; j < 4; ++j) {
                    const unsigned x0 = xa[2 * j], x1 = xa[2 * j + 1];
                    th.u[j] = (x0 & 0xffffu) | (x1 << 16);
                    tl.u[j] = (x0 >> 16) | (x1 & 0xffff0000u);
                }
                ah[s] = th.sv; al[s] = tl.sv;
            }
#pragma unroll
            for (int nt = 0; nt < 4; ++nt) {
                const int fo = ((kt * 4 + nt) * 64 + lane) * 8;
                const short8 bh = *(const short8*)(w2h + fo);
                const short8 bl = *(const short8*)(w2l + fo);
#pragma unroll
                for (int s = 0; s < 2; ++s) {
                    o[s][nt] = MFMA(ah[s], bh, o[s][nt]);
                    o[s][nt] = MFMA(al[s], bh, o[s][nt]);
                    o[s][nt] = MFMA(ah[s], bl, o[s][nt]);
                }
            }
        }

        __builtin_amdgcn_wave_barrier();
#pragma unroll
        for (int s = 0; s < 2; ++s)
#pragma unroll
            for (int nt = 0; nt < 4; ++nt)
#pragma unroll
                for (int r = 0; r < 4; ++r)
                    lds[wid][net][s * 16 + kg * 4 + r][nt * 16 + rowm] = packsplit(o[s][nt][r]);
        __builtin_amdgcn_wave_barrier();

        const int mp = lane >> 2, cs = lane & 3;
        const int Lh = 1 << log2Lh;
#pragma unroll
        for (int s = 0; s < 2; ++s) {
            const int gp = P0 + s * 16 + mp;
            const int P  = gp & 2047;
            const int jj = P & (Lh - 1);
            const int io = 2 * P - jj + (net ? Lh : 0);
            const int gout = b * N_ + io;

            unsigned xe[16];
#pragma unroll
            for (int i = 0; i < 16; ++i) xe[i] = lds[wid][net][s * 16 + mp][cs * 16 + i];

            float z0 = 0.f, z1 = 0.f;
#pragma unroll
            for (int i = 0; i < 16; i += 2) {
                const float4 w = LD4(llr_w + 2 * (cs * 16 + i));
                const float ev0 = unpackf(xe[i]);
                const float ev1 = unpackf(xe[i + 1]);
                z0 = fmaf(ev0, w.x, z0); z1 = fmaf(ev0, w.y, z1);
                z0 = fmaf(ev1, w.z, z0); z1 = fmaf(ev1, w.w, z1);
            }
            z0 += __shfl_xor(z0, 1); z1 += __shfl_xor(z1, 1);
            z0 += __shfl_xor(z0, 2); z1 += __shfl_xor(z1, 2);

            unsigned hiw[8], low[8];
#pragma unroll
            for (int i2 = 0; i2 < 8; ++i2) {
                const unsigned x0 = xe[2 * i2], x1 = xe[2 * i2 + 1];
                hiw[i2] = (x0 & 0xffffu) | (x1 << 16);
                low[i2] = (x0 >> 16) | (x1 & 0xffff0000u);
            }
            {
                const size_t eb = (size_t)gout * D_ + cs * 16;
                *(uint4*)(eo_hi + eb)     = make_uint4(hiw[0], hiw[1], hiw[2], hiw[3]);
                *(uint4*)(eo_hi + eb + 8) = make_uint4(hiw[4], hiw[5], hiw[6], hiw[7]);
                *(uint4*)(eo_lo + eb)     = make_uint4(low[0], low[1], low[2], low[3]);
                *(uint4*)(eo_lo + eb + 8) = make_uint4(low[4], low[5], low[6], low[7]);
            }

            if (cs == 0) {
                const int2 vv = *(const int2*)(v_in + 2 * gp);
                const int vx = (vv.x ^ vv.y) & 1;
                const float zz0 = z0 + llr_b[0], zz1 = z1 + llr_b[1];
                const float m   = fmaxf(zz0, zz1);
                const float ex0 = expf(zz0 - m), ex1 = expf(zz1 - m);
                const float inv = 1.0f / (ex0 + ex1);
                const float p0s = ex0 * inv, p1s = ex1 * inv;
                const float c0  = fminf(fmaxf(p0s, EPS_), 1.0f - EPS_);
                const float c1  = fminf(fmaxf(p1s, EPS_), 1.0f - EPS_);
                const int   lab = net ? (vv.y & 1) : vx;
                const float loss = -logf(lab ? c1 : c0);
                v_out[gout] = net ? vv.y : vx;
                loss_out[(b * T_ + t) * N_ + io] = loss;
                const size_t pb = ((size_t)gout * T_ + t) * 2;
                *(float2*)(pred1 + pb) = make_float2(p0s, p1s);
                *(float2*)(pred2 + pb) = make_float2(p0s, p1s);
            }
        }
    }
}

// ---------------------------------------------------------------------------
// Fused tail: stages t=3..11, e-chunk (512 positions) resident in LDS.
// Swapped-operand MFMA: L1 = W1^T(16x16x32 A) x E^T; L2 = W2^T(16x16x16 A) x H
// with H lane-local from L1 accumulators. 256 blocks x 512 threads.
// ---------------------------------------------------------------------------
__global__ __launch_bounds__(512, 2) void fused_tail(
    const short* __restrict__ e_hi, const short* __restrict__ e_lo,
    const int* __restrict__ v_in,
    const short* __restrict__ p_cn1h, const short* __restrict__ p_cn1l,
    const short* __restrict__ p_bn1h, const short* __restrict__ p_bn1l,
    const short* __restrict__ p_c2th, const short* __restrict__ p_c2tl,
    const short* __restrict__ p_b2th, const short* __restrict__ p_b2tl,
    const float* __restrict__ cn_b1, const float* __restrict__ cn_b2,
    const float* __restrict__ bn_b2, const float* __restrict__ contrib,
    const float* __restrict__ llr_w, const float* __restrict__ llr_b,
    float* __restrict__ loss_out, float* __restrict__ pred1, float* __restrict__ pred2)
{
    __shared__ unsigned e_lds[512 * 68];   // packed hi|lo<<16, row stride 68 (16B-aligned)
    __shared__ int v_lds[512];
    const int tid = threadIdx.x;
    const int b = blockIdx.x >> 3, ch = blockIdx.x & 7;
    const int base_row = b * N_ + ch * 512;

    // ---- chunk load (coalesced: 8 threads per row) ----
    {
        const int seg = tid & 7, r0 = tid >> 3;
#pragma unroll
        for (int it = 0; it < 8; ++it) {
            const int row = it * 64 + r0;
            const size_t g = (size_t)(base_row + row) * D_ + seg * 8;
            const short8 h8 = *(const short8*)(e_hi + g);
            const short8 l8 = *(const short8*)(e_lo + g);
            unsigned u[8];
#pragma unroll
            for (int j2 = 0; j2 < 8; ++j2)
                u[j2] = ((unsigned)(unsigned short)h8[j2]) |
                        (((unsigned)(unsigned short)l8[j2]) << 16);
            unsigned* d = &e_lds[row * 68 + seg * 8];
            *(uint4*)d       = make_uint4(u[0], u[1], u[2], u[3]);
            *(uint4*)(d + 4) = make_uint4(u[4], u[5], u[6], u[7]);
        }
        v_lds[tid] = v_in[base_row + tid];
    }
    __syncthreads();

    const int lane = tid & 63;
    const int pr = lane & 15, kg = lane >> 4;
    const int p_base = (tid >> 6) * 32;    // 8 waves x 32 pairs = 256 pairs

    int Lh = 256;
#pragma unroll 1
    for (int t = 3; t < 12; ++t, Lh >>= 1) {
        // ---- compute phase: LDS reads only ----
        int v1s[2], vx[2];
#pragma unroll
        for (int s = 0; s < 2; ++s) {
            const int p = p_base + s * 16 + pr;
            const int v0 = v_lds[2 * p], v1 = v_lds[2 * p + 1];
            v1s[s] = v1; vx[s] = (v0 ^ v1) & 1;
        }

        f32x4 aC[2][4], aB[2][4];
#pragma unroll
        for (int mt = 0; mt < 4; ++mt) {
            const f4 bc = LD4(cn_b1 + mt * 16 + kg * 4);
#pragma unroll
            for (int s = 0; s < 2; ++s) {
                aC[s][mt] = (f32x4){bc.x, bc.y, bc.z, bc.w};
                const f4 cb = LD4(contrib + vx[s] * 64 + mt * 16 + kg * 4);
                aB[s][mt] = (f32x4){cb.x, cb.y, cb.z, cb.w};
            }
        }

#pragma unroll
        for (int kt = 0; kt < 4; ++kt) {
            short8 Eh[2], El[2];
#pragma unroll
            for (int s = 0; s < 2; ++s) {
                const int p = p_base + s * 16 + pr;
                const unsigned* src = &e_lds[(2 * p + (kt >> 1)) * 68 + (kt & 1) * 32 + kg * 8];
                unsigned xx[8];
                *(uint4*)&xx[0] = *(const uint4*)src;
                *(uint4*)&xx[4] = *(const uint4*)(src + 4);
                union { short8 v; unsigned u[4]; } H, L;
#pragma unroll
                for (int j2 = 0; j2 < 4; ++j2) {
                    H.u[j2] = (xx[2 * j2] & 0xffffu) | (xx[2 * j2 + 1] << 16);
                    L.u[j2] = (xx[2 * j2] >> 16) | (xx[2 * j2 + 1] & 0xffff0000u);
                }
                Eh[s] = H.v; El[s] = L.v;
            }
#pragma unroll
            for (int mt = 0; mt < 4; ++mt) {
                const int fo = ((kt * 4 + mt) * 64 + lane) * 8;
                const short8 wh = *(const short8*)(p_cn1h + fo);
                const short8 wl = *(const short8*)(p_cn1l + fo);
                const short8 uh = *(const short8*)(p_bn1h + fo);
                const short8 ul = *(const short8*)(p_bn1l + fo);
#pragma unroll
                for (int s = 0; s < 2; ++s) {
                    aC[s][mt] = MFMA(wh, Eh[s], aC[s][mt]);
                    aC[s][mt] = MFMA(wl, Eh[s], aC[s][mt]);
                    aC[s][mt] = MFMA(wh, El[s], aC[s][mt]);
                    aB[s][mt] = MFMA(uh, Eh[s], aB[s][mt]);
                    aB[s][mt] = MFMA(ul, Eh[s], aB[s][mt]);
                    aB[s][mt] = MFMA(uh, El[s], aB[s][mt]);
                }
            }
        }

        uint4 pk[2][2][4];
#pragma unroll
        for (int net = 0; net < 2; ++net) {
            const short* __restrict__ w2h = net ? p_b2th : p_c2th;
            const short* __restrict__ w2l = net ? p_b2tl : p_c2tl;
            const float* __restrict__ b2  = net ? bn_b2 : cn_b2;

            // h = relu(acc): lane-local split to 16x16x16 B-frags
            s4b hh[2][4], hl[2][4];
#pragma unroll
            for (int s = 0; s < 2; ++s)
#pragma unroll
                for (int ks = 0; ks < 4; ++ks) {
                    const f32x4 a = net ? aB[s][ks] : aC[s][ks];
#pragma unroll
                    for (int e2 = 0; e2 < 4; ++e2) {
                        short sh, sl2;
                        splitbf(fmaxf(a[e2], 0.f), sh, sl2);
                        hh[s][ks][e2] = sh; hl[s][ks][e2] = sl2;
                    }
                }

            f32x4 o[2][4];
#pragma unroll
            for (int mt2 = 0; mt2 < 4; ++mt2) {
                const f4 bb = LD4(b2 + mt2 * 16 + kg * 4);
#pragma unroll
                for (int s = 0; s < 2; ++s) o[s][mt2] = (f32x4){bb.x, bb.y, bb.z, bb.w};
            }
#pragma unroll
            for (int ks = 0; ks < 4; ++ks)
#pragma unroll
                for (int mt2 = 0; mt2 < 4; ++mt2) {
                    const int fo4 = ((ks * 4 + mt2) * 64 + lane) * 4;
                    const s4b wh = *(const s4b*)(w2h + fo4);
                    const s4b wl = *(const s4b*)(w2l + fo4);
#pragma unroll
                    for (int s = 0; s < 2; ++s) {
                        o[s][mt2] = MFMA16(wh, hh[s][ks], o[s][mt2]);
                        o[s][mt2] = MFMA16(wl, hh[s][ks], o[s][mt2]);
                        o[s][mt2] = MFMA16(wh, hl[s][ks], o[s][mt2]);
                    }
                }

            // pack e_new + llr epilogue (global writes, pre-barrier OK)
#pragma unroll
            for (int s = 0; s < 2; ++s) {
                float z0 = 0.f, z1 = 0.f;
#pragma unroll
                for (int mt2 = 0; mt2 < 4; ++mt2) {
                    pk[net][s][mt2] = make_uint4(
                        packsplit(o[s][mt2][0]), packsplit(o[s][mt2][1]),
                        packsplit(o[s][mt2][2]), packsplit(o[s][mt2][3]));
                    const int f0 = mt2 * 16 + kg * 4;
                    const f4 wA = LD4(llr_w + 2 * f0);
                    const f4 wB = LD4(llr_w + 2 * f0 + 4);
                    z0 += o[s][mt2][0] * wA.x + o[s][mt2][1] * wA.z +
                          o[s][mt2][2] * wB.x + o[s][mt2][3] * wB.z;
                    z1 += o[s][mt2][0] * wA.y + o[s][mt2][1] * wA.w +
                          o[s][mt2][2] * wB.y + o[s][mt2][3] * wB.w;
                }
                z0 += __shfl_xor(z0, 16); z1 += __shfl_xor(z1, 16);
                z0 += __shfl_xor(z0, 32); z1 += __shfl_xor(z1, 32);
                if (kg == 0) {
                    const int p = p_base + s * 16 + pr;
                    const int j = p & (Lh - 1);
                    const int iol = 2 * p - j + (net ? Lh : 0);
                    const int io = ch * 512 + iol;
                    const float zz0 = z0 + llr_b[0], zz1 = z1 + llr_b[1];
                    const float m   = fmaxf(zz0, zz1);
                    const float ex0 = expf(zz0 - m), ex1 = expf(zz1 - m);
                    const float inv = 1.0f / (ex0 + ex1);
                    const float p0s = ex0 * inv, p1s = ex1 * inv;
                    const float c0  = fminf(fmaxf(p0s, EPS_), 1.0f - EPS_);
                    const float c1  = fminf(fmaxf(p1s, EPS_), 1.0f - EPS_);
                    const int   lab = net ? (v1s[s] & 1) : vx[s];
                    const float loss = -logf(lab ? c1 : c0);
                    loss_out[(b * T_ + t) * N_ + io] = loss;
                    const size_t pb = ((size_t)(b * N_ + io) * T_ + t) * 2;
                    *(float2*)(pred1 + pb) = make_float2(p0s, p1s);
                    *(float2*)(pred2 + pb) = make_float2(p0s, p1s);
                }
            }
        }
        __syncthreads();   // all reads of this stage complete before writes

        // ---- write phase ----
#pragma unroll
        for (int net = 0; net < 2; ++net)
#pragma unroll
            for (int s = 0; s < 2; ++s) {
                const int p = p_base + s * 16 + pr;
                const int j = p & (Lh - 1);
                const int iol = 2 * p - j + (net ? Lh : 0);
#pragma unroll
                for (int mt2 = 0; mt2 < 4; ++mt2)
                    *(uint4*)&e_lds[iol * 68 + mt2 * 16 + kg * 4] = pk[net][s][mt2];
                if (kg == 0) v_lds[iol] = net ? v1s[s] : vx[s];
            }
        __syncthreads();   // writes visible before next stage's reads
    }
}

// ---------------------------------------------------------------------------
extern "C" void kernel_launch(void* const* d_in, const int* in_sizes, int n_in,
                              void* d_out, int out_size, void* d_ws, size_t ws_size,
                              hipStream_t stream)
{
    const int*   x      = (const int*)  d_in[0];
    const float* y      = (const float*)d_in[1];
    const float* emb_w1 = (const float*)d_in[2];
    const float* emb_b1 = (const float*)d_in[3];
    const float* emb_w2 = (const float*)d_in[4];
    const float* emb_b2 = (const float*)d_in[5];
    const float* cn_w1  = (const float*)d_in[6];
    const float* cn_b1  = (const float*)d_in[7];
    const float* cn_w2  = (const float*)d_in[8];
    const float* cn_b2  = (const float*)d_in[9];
    const float* bn_w1  = (const float*)d_in[10];
    const float* bn_b1  = (const float*)d_in[11];
    const float* bn_w2  = (const float*)d_in[12];
    const float* bn_b2  = (const float*)d_in[13];
    const float* llr_w  = (const float*)d_in[14];
    const float* llr_b  = (const float*)d_in[15];
    const float* label_emb = (const float*)d_in[16];

    float* out      = (float*)d_out;
    float* loss_out = out;
    float* pred1    = out + (size_t)B_ * T_ * N_;
    float* pred2    = pred1 + (size_t)B_ * N_ * T_ * 2;

    const size_t EPLANE = (size_t)B_ * N_ * D_;
    short* eh_a = (short*)d_ws;
    short* el_a = eh_a + EPLANE;
    short* eh_b = el_a + EPLANE;
    short* el_b = eh_b + EPLANE;
    int*   v_a  = (int*)(el_b + EPLANE);
    int*   v_b  = v_a + B_ * N_;
    short* p_cn1h = (short*)(v_b + B_ * N_);
    short* p_cn1l = p_cn1h + 8192;
    short* p_bn1h = p_cn1l + 8192;
    short* p_bn1l = p_bn1h + 8192;
    short* p_cn2h = p_bn1l + 8192;
    short* p_cn2l = p_cn2h + 4096;
    short* p_bn2h = p_cn2l + 4096;
    short* p_bn2l = p_bn2h + 4096;
    float* contrib = (float*)(p_bn2l + 4096);
    short* p_c2th = (short*)(contrib + 128);
    short* p_c2tl = p_c2th + 4096;
    short* p_b2th = p_c2tl + 4096;
    short* p_b2tl = p_b2th + 4096;

    prep_kernel<<<1, 256, 0, stream>>>(
        cn_w1, cn_w2, bn_w1, bn_w2, bn_b1, label_emb,
        p_cn1h, p_cn1l, p_bn1h, p_bn1l, p_cn2h, p_cn2l, p_bn2h, p_bn2l,
        p_c2th, p_c2tl, p_b2th, p_b2tl, contrib);

    emb_kernel<<<dim3(B_ * N_ / 128), dim3(256), 0, stream>>>(
        x, y, emb_w1, emb_b1, emb_w2, emb_b2, eh_a, el_a, v_a);

    short* ehc = eh_a; short* elc = el_a; short* ehn = eh_b; short* eln = el_b;
    int* vc = v_a; int* vn = v_b;
    for (int t = 0; t < 3; ++t) {
        pair_mfma<<<dim3(B_ * N_ / 2 / 128), dim3(256), 0, stream>>>(
            ehc, elc, vc, ehn, eln, vn,
            p_cn1h, p_cn1l, p_bn1h, p_bn1l, p_cn2h, p_cn2l, p_bn2h, p_bn2l,
            cn_b1, cn_b2, bn_b2, contrib, llr_w, llr_b,
            loss_out, pred1, pred2, t, 11 - t);
        short* t1 = ehc; ehc = ehn; ehn = t1;
        short* t2 = elc; elc = eln; eln = t2;
        int* t3 = vc; vc = vn; vn = t3;
    }

    fused_tail<<<dim3(256), dim3(512), 0, stream>>>(
        ehc, elc, vc,
        p_cn1h, p_cn1l, p_bn1h, p_bn1l,
        p_c2th, p_c2tl, p_b2th, p_b2tl,
        cn_b1, cn_b2, bn_b2, contrib, llr_w, llr_b,
        loss_out, pred1, pred2);
}

// Round 8
// 614.152 us; speedup vs baseline: 1.0056x; 1.0056x over previous
//
#include <hip/hip_runtime.h>
#include <math.h>

#define B_ 32
#define N_ 4096
#define D_ 64
#define T_ 12
#define EPS_ 1e-7f
#define PSTR 65

typedef float4 f4;
#define LD4(p) (*(const float4*)(p))

typedef __attribute__((ext_vector_type(8))) short short8;
typedef __attribute__((ext_vector_type(4))) short s4b;
typedef __attribute__((ext_vector_type(4))) float f32x4;
#define MFMA(a, b, c)   __builtin_amdgcn_mfma_f32_16x16x32_bf16(a, b, c, 0, 0, 0)
#define MFMA16(a, b, c) __builtin_amdgcn_mfma_f32_16x16x16bf16_1k(a, b, c, 0, 0, 0)

__device__ __forceinline__ float f4c(const float4 v, int q) {
    return q == 0 ? v.x : q == 1 ? v.y : q == 2 ? v.z : v.w;
}
__device__ __forceinline__ void fma8(float (&acc)[8], float a, const float4 w0, const float4 w1) {
    acc[0] = fmaf(a, w0.x, acc[0]); acc[1] = fmaf(a, w0.y, acc[1]);
    acc[2] = fmaf(a, w0.z, acc[2]); acc[3] = fmaf(a, w0.w, acc[3]);
    acc[4] = fmaf(a, w1.x, acc[4]); acc[5] = fmaf(a, w1.y, acc[5]);
    acc[6] = fmaf(a, w1.z, acc[6]); acc[7] = fmaf(a, w1.w, acc[7]);
}

// split fp32 -> bf16 hi (truncate) + bf16 lo (truncated remainder)
__device__ __forceinline__ void splitbf(float a, short& h, short& l) {
    unsigned x = __float_as_uint(a);
    h = (short)(x >> 16);
    float r = a - __uint_as_float(x & 0xffff0000u);
    l = (short)(__float_as_uint(r) >> 16);
}
// packed u32: low16 = hi-bf16, high16 = lo-bf16
__device__ __forceinline__ unsigned packsplit(float a) {
    unsigned x = __float_as_uint(a);
    unsigned hib = x & 0xffff0000u;
    float r = a - __uint_as_float(hib);
    return (x >> 16) | (__float_as_uint(r) & 0xffff0000u);
}
__device__ __forceinline__ float unpackf(unsigned p) {
    return __uint_as_float(p << 16) + __uint_as_float(p & 0xffff0000u);
}

// ---------------------------------------------------------------------------
// Prep: pack weights into MFMA fragment order (hi/lo planes) + bn contrib.
// ---------------------------------------------------------------------------
__global__ void prep_kernel(
    const float* __restrict__ cn_w1, const float* __restrict__ cn_w2,
    const float* __restrict__ bn_w1, const float* __restrict__ bn_w2,
    const float* __restrict__ bn_b1, const float* __restrict__ label_emb,
    short* __restrict__ p_cn1h, short* __restrict__ p_cn1l,
    short* __restrict__ p_bn1h, short* __restrict__ p_bn1l,
    short* __restrict__ p_cn2h, short* __restrict__ p_cn2l,
    short* __restrict__ p_bn2h, short* __restrict__ p_bn2l,
    short* __restrict__ p_c2th, short* __restrict__ p_c2tl,
    short* __restrict__ p_b2th, short* __restrict__ p_b2tl,
    float* __restrict__ contrib)
{
    const int tid = threadIdx.x;
    for (int idx = tid; idx < 8192; idx += 256) {   // w1 packs (K=128)
        const int e = idx & 7, l = (idx >> 3) & 63, fb = idx >> 9;
        const int kt = fb >> 2, nt = fb & 3;
        const int k = kt * 32 + (l >> 4) * 8 + e;
        const int n = nt * 16 + (l & 15);
        short h, lo;
        splitbf(cn_w1[k * 64 + n], h, lo); p_cn1h[idx] = h; p_cn1l[idx] = lo;
        splitbf(bn_w1[k * 64 + n], h, lo); p_bn1h[idx] = h; p_bn1l[idx] = lo;
    }
    for (int idx = tid; idx < 4096; idx += 256) {   // w2 packs (K=64, 16x16x32 B)
        const int e = idx & 7, l = (idx >> 3) & 63, fb = idx >> 9;
        const int kt = fb >> 2, nt = fb & 3;
        const int k = kt * 32 + (l >> 4) * 8 + e;
        const int n = nt * 16 + (l & 15);
        short h, lo;
        splitbf(cn_w2[k * 64 + n], h, lo); p_cn2h[idx] = h; p_cn2l[idx] = lo;
        splitbf(bn_w2[k * 64 + n], h, lo); p_bn2h[idx] = h; p_bn2l[idx] = lo;
    }
    for (int idx = tid; idx < 4096; idx += 256) {   // w2^T packs (16x16x16 A)
        const int e = idx & 3, l = (idx >> 2) & 63, fb = idx >> 8;
        const int ks = fb >> 2, mt2 = fb & 3;
        const int k = ks * 16 + (l >> 4) * 4 + e;
        const int n = mt2 * 16 + (l & 15);
        short h, lo;
        splitbf(cn_w2[k * 64 + n], h, lo); p_c2th[idx] = h; p_c2tl[idx] = lo;
        splitbf(bn_w2[k * 64 + n], h, lo); p_b2th[idx] = h; p_b2tl[idx] = lo;
    }
    if (tid < 128) {                                 // contrib[c][n] = b1[n] + le[c]@bn_w1[128:]
        const int c = tid >> 6, n = tid & 63;
        float s = bn_b1[n];
        for (int kk = 0; kk < 64; ++kk)
            s = fmaf(label_emb[c * 64 + kk], bn_w1[(128 + kk) * 64 + n], s);
        contrib[c * 64 + n] = s;
    }
}

// ---------------------------------------------------------------------------
// Embedding (fp32 vector; small). Writes e as bf16 hi/lo planes.
// ---------------------------------------------------------------------------
__global__ __launch_bounds__(256, 4) void emb_kernel(
    const int* __restrict__ x, const float* __restrict__ y,
    const float* __restrict__ w1, const float* __restrict__ b1,
    const float* __restrict__ w2, const float* __restrict__ b2,
    short* __restrict__ e_hi, short* __restrict__ e_lo, int* __restrict__ v_out)
{
    __shared__ float h_lds[128 * PSTR];
    const int tid = threadIdx.x;
    const int s   = tid & 7;
    const int g   = tid >> 3;
    const int jj0 = s * 8;
    const int i0  = (blockIdx.x * 32 + g) * 4;

    {
        f4 wa0 = LD4(w1 + jj0),      wa1 = LD4(w1 + jj0 + 4);
        f4 wb0 = LD4(w1 + D_ + jj0), wb1 = LD4(w1 + D_ + jj0 + 4);
        f4 bb0 = LD4(b1 + jj0),      bb1 = LD4(b1 + jj0 + 4);
#pragma unroll
        for (int pp = 0; pp < 4; ++pp) {
            const float2 yv = *(const float2*)(y + 2 * (i0 + pp));
            f4 h0, h1;
            h0.x = fmaxf(fmaf(yv.y, wb0.x, fmaf(yv.x, wa0.x, bb0.x)), 0.f);
            h0.y = fmaxf(fmaf(yv.y, wb0.y, fmaf(yv.x, wa0.y, bb0.y)), 0.f);
            h0.z = fmaxf(fmaf(yv.y, wb0.z, fmaf(yv.x, wa0.z, bb0.z)), 0.f);
            h0.w = fmaxf(fmaf(yv.y, wb0.w, fmaf(yv.x, wa0.w, bb0.w)), 0.f);
            h1.x = fmaxf(fmaf(yv.y, wb1.x, fmaf(yv.x, wa1.x, bb1.x)), 0.f);
            h1.y = fmaxf(fmaf(yv.y, wb1.y, fmaf(yv.x, wa1.y, bb1.y)), 0.f);
            h1.z = fmaxf(fmaf(yv.y, wb1.z, fmaf(yv.x, wa1.z, bb1.z)), 0.f);
            h1.w = fmaxf(fmaf(yv.y, wb1.w, fmaf(yv.x, wa1.w, bb1.w)), 0.f);
            float* hp = h_lds + (g * 4 + pp) * PSTR + jj0;
            *(f4*)hp = h0; *(f4*)(hp + 4) = h1;
        }
    }
    __syncthreads();

    float o[4][8];
    {
        f4 b20 = LD4(b2 + jj0), b21 = LD4(b2 + jj0 + 4);
#pragma unroll
        for (int pp = 0; pp < 4; ++pp) {
            o[pp][0]=b20.x; o[pp][1]=b20.y; o[pp][2]=b20.z; o[pp][3]=b20.w;
            o[pp][4]=b21.x; o[pp][5]=b21.y; o[pp][6]=b21.z; o[pp][7]=b21.w;
        }
    }
#pragma unroll 2
    for (int k4 = 0; k4 < 16; ++k4) {
        const f4 x0 = LD4(h_lds + (g * 4 + 0) * PSTR + 4 * k4);
        const f4 x1 = LD4(h_lds + (g * 4 + 1) * PSTR + 4 * k4);
        const f4 x2 = LD4(h_lds + (g * 4 + 2) * PSTR + 4 * k4);
        const f4 x3 = LD4(h_lds + (g * 4 + 3) * PSTR + 4 * k4);
        const float* wk = w2 + (4 * k4) * D_ + jj0;
#pragma unroll
        for (int q = 0; q < 4; ++q) {
            const f4 wa = LD4(wk + q * D_), wb = LD4(wk + q * D_ + 4);
            fma8(o[0], f4c(x0, q), wa, wb);
            fma8(o[1], f4c(x1, q), wa, wb);
            fma8(o[2], f4c(x2, q), wa, wb);
            fma8(o[3], f4c(x3, q), wa, wb);
        }
    }

#pragma unroll
    for (int pp = 0; pp < 4; ++pp) {
        const size_t base = (size_t)(i0 + pp) * D_ + jj0;
        union { short s[8]; uint4 v; } uh, ul;
#pragma unroll
        for (int q = 0; q < 8; ++q) splitbf(o[pp][q], uh.s[q], ul.s[q]);
        *(uint4*)(e_hi + base) = uh.v;
        *(uint4*)(e_lo + base) = ul.v;
    }
    if (s < 4) v_out[i0 + s] = x[i0 + s];
}

// ---------------------------------------------------------------------------
// Global tree stage (t = 0,1,2). Preds go to compact scratch (no RMW scatter).
// ---------------------------------------------------------------------------
__global__ __launch_bounds__(256, 2) void pair_mfma(
    const short* __restrict__ e_hi, const short* __restrict__ e_lo,
    const int* __restrict__ v_in,
    short* __restrict__ eo_hi, short* __restrict__ eo_lo, int* __restrict__ v_out,
    const short* __restrict__ p_cn1h, const short* __restrict__ p_cn1l,
    const short* __restrict__ p_bn1h, const short* __restrict__ p_bn1l,
    const short* __restrict__ p_cn2h, const short* __restrict__ p_cn2l,
    const short* __restrict__ p_bn2h, const short* __restrict__ p_bn2l,
    const float* __restrict__ cn_b1, const float* __restrict__ cn_b2,
    const float* __restrict__ bn_b2, const float* __restrict__ contrib,
    const float* __restrict__ llr_w, const float* __restrict__ llr_b,
    float* __restrict__ loss_out, float2* __restrict__ pscr,
    int t, int log2Lh)
{
    __shared__ unsigned int lds[4][2][32][68];
    const int tid  = threadIdx.x;
    const int wid  = tid >> 6, lane = tid & 63;
    const int rowm = lane & 15, kg = lane >> 4;
    const int P0   = (blockIdx.x * 4 + wid) * 32;
    const int b    = P0 >> 11;

    int vxm[2][4];
#pragma unroll
    for (int s = 0; s < 2; ++s)
#pragma unroll
        for (int r = 0; r < 4; ++r) {
            const int2 vv = *(const int2*)(v_in + 2 * (P0 + s * 16 + kg * 4 + r));
            vxm[s][r] = (vv.x ^ vv.y) & 1;
        }

    f32x4 aC[2][4], aB[2][4];
#pragma unroll
    for (int nt = 0; nt < 4; ++nt) {
        const float bc = cn_b1[nt * 16 + rowm];
#pragma unroll
        for (int s = 0; s < 2; ++s) {
            aC[s][nt] = (f32x4){bc, bc, bc, bc};
            f32x4 ab;
#pragma unroll
            for (int r = 0; r < 4; ++r) ab[r] = contrib[vxm[s][r] * 64 + nt * 16 + rowm];
            aB[s][nt] = ab;
        }
    }

#pragma unroll
    for (int kt = 0; kt < 4; ++kt) {
        short8 Ah[2], Al[2];
#pragma unroll
        for (int s = 0; s < 2; ++s) {
            const size_t pos = (size_t)(2 * (P0 + s * 16 + rowm) + (kt >> 1));
            const int off = (kt & 1) * 32 + kg * 8;
            Ah[s] = *(const short8*)(e_hi + pos * D_ + off);
            Al[s] = *(const short8*)(e_lo + pos * D_ + off);
        }
#pragma unroll
        for (int nt = 0; nt < 4; ++nt) {
            const int fo = ((kt * 4 + nt) * 64 + lane) * 8;
            const short8 bh = *(const short8*)(p_cn1h + fo);
            const short8 bl = *(const short8*)(p_cn1l + fo);
            const short8 ch = *(const short8*)(p_bn1h + fo);
            const short8 cl = *(const short8*)(p_bn1l + fo);
#pragma unroll
            for (int s = 0; s < 2; ++s) {
                aC[s][nt] = MFMA(Ah[s], bh, aC[s][nt]);
                aC[s][nt] = MFMA(Al[s], bh, aC[s][nt]);
                aC[s][nt] = MFMA(Ah[s], bl, aC[s][nt]);
                aB[s][nt] = MFMA(Ah[s], ch, aB[s][nt]);
                aB[s][nt] = MFMA(Al[s], ch, aB[s][nt]);
                aB[s][nt] = MFMA(Ah[s], cl, aB[s][nt]);
            }
        }
    }

#pragma unroll
    for (int s = 0; s < 2; ++s)
#pragma unroll
        for (int nt = 0; nt < 4; ++nt)
#pragma unroll
            for (int r = 0; r < 4; ++r) {
                lds[wid][0][s * 16 + kg * 4 + r][nt * 16 + rowm] = packsplit(fmaxf(aC[s][nt][r], 0.f));
                lds[wid][1][s * 16 + kg * 4 + r][nt * 16 + rowm] = packsplit(fmaxf(aB[s][nt][r], 0.f));
            }
    __builtin_amdgcn_wave_barrier();

#pragma unroll
    for (int net = 0; net < 2; ++net) {
        const short* __restrict__ w2h = net ? p_bn2h : p_cn2h;
        const short* __restrict__ w2l = net ? p_bn2l : p_cn2l;
        const float* __restrict__ b2  = net ? bn_b2 : cn_b2;

        f32x4 o[2][4];
#pragma unroll
        for (int nt = 0; nt < 4; ++nt) {
            const float bb = b2[nt * 16 + rowm];
#pragma unroll
            for (int s = 0; s < 2; ++s) o[s][nt] = (f32x4){bb, bb, bb, bb};
        }

#pragma unroll
        for (int kt = 0; kt < 2; ++kt) {
            short8 ah[2], al[2];
#pragma unroll
            for (int s = 0; s < 2; ++s) {
                unsigned xa[8];
#pragma unroll
                for (int e2 = 0; e2 < 8; ++e2)
                    xa[e2] = lds[wid][net][s * 16 + rowm][kt * 32 + kg * 8 + e2];
                union { short8 sv; unsigned u[4]; } th, tl;
#pragma unroll
                for (int j = 0; j < 4; ++j) {
                    const unsigned x0 = xa[2 * j], x1 = xa[2 * j + 1];
                    th.u[j] = (x0 & 0xffffu) | (x1 << 16);
                    tl.u[j] = (x0 >> 16) | (x1 & 0xffff0000u);
                }
                ah[s] = th.sv; al[s] = tl.sv;
            }
#pragma unroll
            for (int nt = 0; nt < 4; ++nt) {
                const int fo = ((kt * 4 + nt) * 64 + lane) * 8;
                const short8 bh = *(const short8*)(w2h + fo);
                const short8 bl = *(const short8*)(w2l + fo);
#pragma unroll
                for (int s = 0; s < 2; ++s) {
                    o[s][nt] = MFMA(ah[s], bh, o[s][nt]);
                    o[s][nt] = MFMA(al[s], bh, o[s][nt]);
                    o[s][nt] = MFMA(ah[s], bl, o[s][nt]);
                }
            }
        }

        __builtin_amdgcn_wave_barrier();
#pragma unroll
        for (int s = 0; s < 2; ++s)
#pragma unroll
            for (int nt = 0; nt < 4; ++nt)
#pragma unroll
                for (int r = 0; r < 4; ++r)
                    lds[wid][net][s * 16 + kg * 4 + r][nt * 16 + rowm] = packsplit(o[s][nt][r]);
        __builtin_amdgcn_wave_barrier();

        const int mp = lane >> 2, cs = lane & 3;
        const int Lh = 1 << log2Lh;
#pragma unroll
        for (int s = 0; s < 2; ++s) {
            const int gp = P0 + s * 16 + mp;
            const int P  = gp & 2047;
            const int jj = P & (Lh - 1);
            const int io = 2 * P - jj + (net ? Lh : 0);
            const int gout = b * N_ + io;

            unsigned xe[16];
#pragma unroll
            for (int i = 0; i < 16; ++i) xe[i] = lds[wid][net][s * 16 + mp][cs * 16 + i];

            float z0 = 0.f, z1 = 0.f;
#pragma unroll
            for (int i = 0; i < 16; i += 2) {
                const float4 w = LD4(llr_w + 2 * (cs * 16 + i));
                const float ev0 = unpackf(xe[i]);
                const float ev1 = unpackf(xe[i + 1]);
                z0 = fmaf(ev0, w.x, z0); z1 = fmaf(ev0, w.y, z1);
                z0 = fmaf(ev1, w.z, z0); z1 = fmaf(ev1, w.w, z1);
            }
            z0 += __shfl_xor(z0, 1); z1 += __shfl_xor(z1, 1);
            z0 += __shfl_xor(z0, 2); z1 += __shfl_xor(z1, 2);

            unsigned hiw[8], low[8];
#pragma unroll
            for (int i2 = 0; i2 < 8; ++i2) {
                const unsigned x0 = xe[2 * i2], x1 = xe[2 * i2 + 1];
                hiw[i2] = (x0 & 0xffffu) | (x1 << 16);
                low[i2] = (x0 >> 16) | (x1 & 0xffff0000u);
            }
            {
                const size_t eb = (size_t)gout * D_ + cs * 16;
                *(uint4*)(eo_hi + eb)     = make_uint4(hiw[0], hiw[1], hiw[2], hiw[3]);
                *(uint4*)(eo_hi + eb + 8) = make_uint4(hiw[4], hiw[5], hiw[6], hiw[7]);
                *(uint4*)(eo_lo + eb)     = make_uint4(low[0], low[1], low[2], low[3]);
                *(uint4*)(eo_lo + eb + 8) = make_uint4(low[4], low[5], low[6], low[7]);
            }

            if (cs == 0) {
                const int2 vv = *(const int2*)(v_in + 2 * gp);
                const int vx = (vv.x ^ vv.y) & 1;
                const float zz0 = z0 + llr_b[0], zz1 = z1 + llr_b[1];
                const float m   = fmaxf(zz0, zz1);
                const float ex0 = expf(zz0 - m), ex1 = expf(zz1 - m);
                const float inv = 1.0f / (ex0 + ex1);
                const float p0s = ex0 * inv, p1s = ex1 * inv;
                const float c0  = fminf(fmaxf(p0s, EPS_), 1.0f - EPS_);
                const float c1  = fminf(fmaxf(p1s, EPS_), 1.0f - EPS_);
                const int   lab = net ? (vv.y & 1) : vx;
                const float loss = -logf(lab ? c1 : c0);
                v_out[gout] = net ? vv.y : vx;
                loss_out[(b * T_ + t) * N_ + io] = loss;
                pscr[(size_t)(b * T_ + t) * N_ + io] = make_float2(p0s, p1s);
            }
        }
    }
}

// ---------------------------------------------------------------------------
// Fused tail: stages t=3..11, e-chunk (512 positions) in LDS. Preds -> pscr.
// ---------------------------------------------------------------------------
__global__ __launch_bounds__(512, 2) void fused_tail(
    const short* __restrict__ e_hi, const short* __restrict__ e_lo,
    const int* __restrict__ v_in,
    const short* __restrict__ p_cn1h, const short* __restrict__ p_cn1l,
    const short* __restrict__ p_bn1h, const short* __restrict__ p_bn1l,
    const short* __restrict__ p_c2th, const short* __restrict__ p_c2tl,
    const short* __restrict__ p_b2th, const short* __restrict__ p_b2tl,
    const float* __restrict__ cn_b1, const float* __restrict__ cn_b2,
    const float* __restrict__ bn_b2, const float* __restrict__ contrib,
    const float* __restrict__ llr_w, const float* __restrict__ llr_b,
    float* __restrict__ loss_out, float2* __restrict__ pscr)
{
    __shared__ unsigned e_lds[512 * 68];
    __shared__ int v_lds[512];
    const int tid = threadIdx.x;
    const int b = blockIdx.x >> 3, ch = blockIdx.x & 7;
    const int base_row = b * N_ + ch * 512;

    {
        const int seg = tid & 7, r0 = tid >> 3;
#pragma unroll
        for (int it = 0; it < 8; ++it) {
            const int row = it * 64 + r0;
            const size_t g = (size_t)(base_row + row) * D_ + seg * 8;
            const short8 h8 = *(const short8*)(e_hi + g);
            const short8 l8 = *(const short8*)(e_lo + g);
            unsigned u[8];
#pragma unroll
            for (int j2 = 0; j2 < 8; ++j2)
                u[j2] = ((unsigned)(unsigned short)h8[j2]) |
                        (((unsigned)(unsigned short)l8[j2]) << 16);
            unsigned* d = &e_lds[row * 68 + seg * 8];
            *(uint4*)d       = make_uint4(u[0], u[1], u[2], u[3]);
            *(uint4*)(d + 4) = make_uint4(u[4], u[5], u[6], u[7]);
        }
        v_lds[tid] = v_in[base_row + tid];
    }
    __syncthreads();

    const int lane = tid & 63;
    const int pr = lane & 15, kg = lane >> 4;
    const int p_base = (tid >> 6) * 32;

    int Lh = 256;
#pragma unroll 1
    for (int t = 3; t < 12; ++t, Lh >>= 1) {
        int v1s[2], vx[2];
#pragma unroll
        for (int s = 0; s < 2; ++s) {
            const int p = p_base + s * 16 + pr;
            const int v0 = v_lds[2 * p], v1 = v_lds[2 * p + 1];
            v1s[s] = v1; vx[s] = (v0 ^ v1) & 1;
        }

        f32x4 aC[2][4], aB[2][4];
#pragma unroll
        for (int mt = 0; mt < 4; ++mt) {
            const f4 bc = LD4(cn_b1 + mt * 16 + kg * 4);
#pragma unroll
            for (int s = 0; s < 2; ++s) {
                aC[s][mt] = (f32x4){bc.x, bc.y, bc.z, bc.w};
                const f4 cb = LD4(contrib + vx[s] * 64 + mt * 16 + kg * 4);
                aB[s][mt] = (f32x4){cb.x, cb.y, cb.z, cb.w};
            }
        }

#pragma unroll
        for (int kt = 0; kt < 4; ++kt) {
            short8 Eh[2], El[2];
#pragma unroll
            for (int s = 0; s < 2; ++s) {
                const int p = p_base + s * 16 + pr;
                const unsigned* src = &e_lds[(2 * p + (kt >> 1)) * 68 + (kt & 1) * 32 + kg * 8];
                unsigned xx[8];
                *(uint4*)&xx[0] = *(const uint4*)src;
                *(uint4*)&xx[4] = *(const uint4*)(src + 4);
                union { short8 v; unsigned u[4]; } H, L;
#pragma unroll
                for (int j2 = 0; j2 < 4; ++j2) {
                    H.u[j2] = (xx[2 * j2] & 0xffffu) | (xx[2 * j2 + 1] << 16);
                    L.u[j2] = (xx[2 * j2] >> 16) | (xx[2 * j2 + 1] & 0xffff0000u);
                }
                Eh[s] = H.v; El[s] = L.v;
            }
#pragma unroll
            for (int mt = 0; mt < 4; ++mt) {
                const int fo = ((kt * 4 + mt) * 64 + lane) * 8;
                const short8 wh = *(const short8*)(p_cn1h + fo);
                const short8 wl = *(const short8*)(p_cn1l + fo);
                const short8 uh = *(const short8*)(p_bn1h + fo);
                const short8 ul = *(const short8*)(p_bn1l + fo);
#pragma unroll
                for (int s = 0; s < 2; ++s) {
                    aC[s][mt] = MFMA(wh, Eh[s], aC[s][mt]);
                    aC[s][mt] = MFMA(wl, Eh[s], aC[s][mt]);
                    aC[s][mt] = MFMA(wh, El[s], aC[s][mt]);
                    aB[s][mt] = MFMA(uh, Eh[s], aB[s][mt]);
                    aB[s][mt] = MFMA(ul, Eh[s], aB[s][mt]);
                    aB[s][mt] = MFMA(uh, El[s], aB[s][mt]);
                }
            }
        }

        uint4 pk[2][2][4];
#pragma unroll
        for (int net = 0; net < 2; ++net) {
            const short* __restrict__ w2h = net ? p_b2th : p_c2th;
            const short* __restrict__ w2l = net ? p_b2tl : p_c2tl;
            const float* __restrict__ b2  = net ? bn_b2 : cn_b2;

            s4b hh[2][4], hl[2][4];
#pragma unroll
            for (int s = 0; s < 2; ++s)
#pragma unroll
                for (int ks = 0; ks < 4; ++ks) {
                    const f32x4 a = net ? aB[s][ks] : aC[s][ks];
#pragma unroll
                    for (int e2 = 0; e2 < 4; ++e2) {
                        short sh, sl2;
                        splitbf(fmaxf(a[e2], 0.f), sh, sl2);
                        hh[s][ks][e2] = sh; hl[s][ks][e2] = sl2;
                    }
                }

            f32x4 o[2][4];
#pragma unroll
            for (int mt2 = 0; mt2 < 4; ++mt2) {
                const f4 bb = LD4(b2 + mt2 * 16 + kg * 4);
#pragma unroll
                for (int s = 0; s < 2; ++s) o[s][mt2] = (f32x4){bb.x, bb.y, bb.z, bb.w};
            }
#pragma unroll
            for (int ks = 0; ks < 4; ++ks)
#pragma unroll
                for (int mt2 = 0; mt2 < 4; ++mt2) {
                    const int fo4 = ((ks * 4 + mt2) * 64 + lane) * 4;
                    const s4b wh = *(const s4b*)(w2h + fo4);
                    const s4b wl = *(const s4b*)(w2l + fo4);
#pragma unroll
                    for (int s = 0; s < 2; ++s) {
                        o[s][mt2] = MFMA16(wh, hh[s][ks], o[s][mt2]);
                        o[s][mt2] = MFMA16(wl, hh[s][ks], o[s][mt2]);
                        o[s][mt2] = MFMA16(wh, hl[s][ks], o[s][mt2]);
                    }
                }

#pragma unroll
            for (int s = 0; s < 2; ++s) {
                float z0 = 0.f, z1 = 0.f;
#pragma unroll
                for (int mt2 = 0; mt2 < 4; ++mt2) {
                    pk[net][s][mt2] = make_uint4(
                        packsplit(o[s][mt2][0]), packsplit(o[s][mt2][1]),
                        packsplit(o[s][mt2][2]), packsplit(o[s][mt2][3]));
                    const int f0 = mt2 * 16 + kg * 4;
                    const f4 wA = LD4(llr_w + 2 * f0);
                    const f4 wB = LD4(llr_w + 2 * f0 + 4);
                    z0 += o[s][mt2][0] * wA.x + o[s][mt2][1] * wA.z +
                          o[s][mt2][2] * wB.x + o[s][mt2][3] * wB.z;
                    z1 += o[s][mt2][0] * wA.y + o[s][mt2][1] * wA.w +
                          o[s][mt2][2] * wB.y + o[s][mt2][3] * wB.w;
                }
                z0 += __shfl_xor(z0, 16); z1 += __shfl_xor(z1, 16);
                z0 += __shfl_xor(z0, 32); z1 += __shfl_xor(z1, 32);
                if (kg == 0) {
                    const int p = p_base + s * 16 + pr;
                    const int j = p & (Lh - 1);
                    const int iol = 2 * p - j + (net ? Lh : 0);
                    const int io = ch * 512 + iol;
                    const float zz0 = z0 + llr_b[0], zz1 = z1 + llr_b[1];
                    const float m   = fmaxf(zz0, zz1);
                    const float ex0 = expf(zz0 - m), ex1 = expf(zz1 - m);
                    const float inv = 1.0f / (ex0 + ex1);
                    const float p0s = ex0 * inv, p1s = ex1 * inv;
                    const float c0  = fminf(fmaxf(p0s, EPS_), 1.0f - EPS_);
                    const float c1  = fminf(fmaxf(p1s, EPS_), 1.0f - EPS_);
                    const int   lab = net ? (v1s[s] & 1) : vx[s];
                    const float loss = -logf(lab ? c1 : c0);
                    loss_out[(b * T_ + t) * N_ + io] = loss;
                    pscr[(size_t)(b * T_ + t) * N_ + io] = make_float2(p0s, p1s);
                }
            }
        }
        __syncthreads();

#pragma unroll
        for (int net = 0; net < 2; ++net)
#pragma unroll
            for (int s = 0; s < 2; ++s) {
                const int p = p_base + s * 16 + pr;
                const int j = p & (Lh - 1);
                const int iol = 2 * p - j + (net ? Lh : 0);
#pragma unroll
                for (int mt2 = 0; mt2 < 4; ++mt2)
                    *(uint4*)&e_lds[iol * 68 + mt2 * 16 + kg * 4] = pk[net][s][mt2];
                if (kg == 0) v_lds[iol] = net ? v1s[s] : vx[s];
            }
        __syncthreads();
    }
}

// ---------------------------------------------------------------------------
// Final: transpose pscr [b][t][io](2) -> pred [b][io][t][2], write both copies.
// Reads coalesced per t; each thread writes its position's 96B row contiguously.
// ---------------------------------------------------------------------------
__global__ __launch_bounds__(256) void pred_epilogue(
    const float2* __restrict__ pscr,
    float* __restrict__ pred1, float* __restrict__ pred2)
{
    const int idx = blockIdx.x * 256 + threadIdx.x;   // b*N + io
    const int b = idx >> 12, io = idx & (N_ - 1);
    float2 v[T_];
#pragma unroll
    for (int t = 0; t < T_; ++t)
        v[t] = pscr[(size_t)(b * T_ + t) * N_ + io];
    float* d1 = pred1 + (size_t)idx * (T_ * 2);
    float* d2 = pred2 + (size_t)idx * (T_ * 2);
#pragma unroll
    for (int q = 0; q < 6; ++q) {
        const f4 w = make_float4(v[2 * q].x, v[2 * q].y, v[2 * q + 1].x, v[2 * q + 1].y);
        *(f4*)(d1 + 4 * q) = w;
        *(f4*)(d2 + 4 * q) = w;
    }
}

// ---------------------------------------------------------------------------
extern "C" void kernel_launch(void* const* d_in, const int* in_sizes, int n_in,
                              void* d_out, int out_size, void* d_ws, size_t ws_size,
                              hipStream_t stream)
{
    const int*   x      = (const int*)  d_in[0];
    const float* y      = (const float*)d_in[1];
    const float* emb_w1 = (const float*)d_in[2];
    const float* emb_b1 = (const float*)d_in[3];
    const float* emb_w2 = (const float*)d_in[4];
    const float* emb_b2 = (const float*)d_in[5];
    const float* cn_w1  = (const float*)d_in[6];
    const float* cn_b1  = (const float*)d_in[7];
    const float* cn_w2  = (const float*)d_in[8];
    const float* cn_b2  = (const float*)d_in[9];
    const float* bn_w1  = (const float*)d_in[10];
    const float* bn_b1  = (const float*)d_in[11];
    const float* bn_w2  = (const float*)d_in[12];
    const float* bn_b2  = (const float*)d_in[13];
    const float* llr_w  = (const float*)d_in[14];
    const float* llr_b  = (const float*)d_in[15];
    const float* label_emb = (const float*)d_in[16];

    float* out      = (float*)d_out;
    float* loss_out = out;
    float* pred1    = out + (size_t)B_ * T_ * N_;
    float* pred2    = pred1 + (size_t)B_ * N_ * T_ * 2;

    const size_t EPLANE = (size_t)B_ * N_ * D_;
    short* eh_a = (short*)d_ws;
    short* el_a = eh_a + EPLANE;
    short* eh_b = el_a + EPLANE;
    short* el_b = eh_b + EPLANE;
    int*   v_a  = (int*)(el_b + EPLANE);
    int*   v_b  = v_a + B_ * N_;
    float2* pscr = (float2*)(v_b + B_ * N_);          // B*T*N float2 (12.6 MB)
    short* p_cn1h = (short*)(pscr + (size_t)B_ * T_ * N_);
    short* p_cn1l = p_cn1h + 8192;
    short* p_bn1h = p_cn1l + 8192;
    short* p_bn1l = p_bn1h + 8192;
    short* p_cn2h = p_bn1l + 8192;
    short* p_cn2l = p_cn2h + 4096;
    short* p_bn2h = p_cn2l + 4096;
    short* p_bn2l = p_bn2h + 4096;
    float* contrib = (float*)(p_bn2l + 4096);
    short* p_c2th = (short*)(contrib + 128);
    short* p_c2tl = p_c2th + 4096;
    short* p_b2th = p_c2tl + 4096;
    short* p_b2tl = p_b2th + 4096;

    prep_kernel<<<1, 256, 0, stream>>>(
        cn_w1, cn_w2, bn_w1, bn_w2, bn_b1, label_emb,
        p_cn1h, p_cn1l, p_bn1h, p_bn1l, p_cn2h, p_cn2l, p_bn2h, p_bn2l,
        p_c2th, p_c2tl, p_b2th, p_b2tl, contrib);

    emb_kernel<<<dim3(B_ * N_ / 128), dim3(256), 0, stream>>>(
        x, y, emb_w1, emb_b1, emb_w2, emb_b2, eh_a, el_a, v_a);

    short* ehc = eh_a; short* elc = el_a; short* ehn = eh_b; short* eln = el_b;
    int* vc = v_a; int* vn = v_b;
    for (int t = 0; t < 3; ++t) {
        pair_mfma<<<dim3(B_ * N_ / 2 / 128), dim3(256), 0, stream>>>(
            ehc, elc, vc, ehn, eln, vn,
            p_cn1h, p_cn1l, p_bn1h, p_bn1l, p_cn2h, p_cn2l, p_bn2h, p_bn2l,
            cn_b1, cn_b2, bn_b2, contrib, llr_w, llr_b,
            loss_out, pscr, t, 11 - t);
        short* t1 = ehc; ehc = ehn; ehn = t1;
        short* t2 = elc; elc = eln; eln = t2;
        int* t3 = vc; vc = vn; vn = t3;
    }

    fused_tail<<<dim3(256), dim3(512), 0, stream>>>(
        ehc, elc, vc,
        p_cn1h, p_cn1l, p_bn1h, p_bn1l,
        p_c2th, p_c2tl, p_b2th, p_b2tl,
        cn_b1, cn_b2, bn_b2, contrib, llr_w, llr_b,
        loss_out, pscr);

    pred_epilogue<<<dim3(B_ * N_ / 256), dim3(256), 0, stream>>>(
        pscr, pred1, pred2);
}

// Round 9
// 295.594 us; speedup vs baseline: 2.0892x; 2.0777x over previous
//
#include <hip/hip_runtime.h>
#include <math.h>

#define B_ 32
#define N_ 4096
#define D_ 64
#define T_ 12
#define EPS_ 1e-7f
#define PSTR 65

typedef float4 f4;
#define LD4(p) (*(const float4*)(p))

typedef __attribute__((ext_vector_type(8))) short short8;
typedef __attribute__((ext_vector_type(4))) short s4b;
typedef __attribute__((ext_vector_type(4))) float f32x4;
#define MFMA(a, b, c)   __builtin_amdgcn_mfma_f32_16x16x32_bf16(a, b, c, 0, 0, 0)
#define MFMA16(a, b, c) __builtin_amdgcn_mfma_f32_16x16x16bf16_1k(a, b, c, 0, 0, 0)

// weight blob LDS offsets (shorts)
#define OFF_C1H 0
#define OFF_C1L 8192
#define OFF_B1H 16384
#define OFF_B1L 24576
#define OFF_C2TH 32768
#define OFF_C2TL 36864
#define OFF_B2TH 40960
#define OFF_B2TL 45056
#define WBLOB_SHORTS 49152

__device__ __forceinline__ float f4c(const float4 v, int q) {
    return q == 0 ? v.x : q == 1 ? v.y : q == 2 ? v.z : v.w;
}
__device__ __forceinline__ void fma8(float (&acc)[8], float a, const float4 w0, const float4 w1) {
    acc[0] = fmaf(a, w0.x, acc[0]); acc[1] = fmaf(a, w0.y, acc[1]);
    acc[2] = fmaf(a, w0.z, acc[2]); acc[3] = fmaf(a, w0.w, acc[3]);
    acc[4] = fmaf(a, w1.x, acc[4]); acc[5] = fmaf(a, w1.y, acc[5]);
    acc[6] = fmaf(a, w1.z, acc[6]); acc[7] = fmaf(a, w1.w, acc[7]);
}

__device__ __forceinline__ void splitbf(float a, short& h, short& l) {
    unsigned x = __float_as_uint(a);
    h = (short)(x >> 16);
    float r = a - __uint_as_float(x & 0xffff0000u);
    l = (short)(__float_as_uint(r) >> 16);
}

// sigma: involutive feature permutation for e-storage (swap bits[5:4]<->[3:2])
__device__ __forceinline__ int sigma_(int f) {
    return (((f >> 2) & 3) << 4) | (((f >> 4) & 3) << 2) | (f & 3);
}

// ---------------------------------------------------------------------------
// Prep: pack weights (hi/lo planes) into one contiguous blob + bn contrib.
// w1 packs: A/B-frag 16x16x32, k-dim uses sigma-permuted e-features.
// w2t packs: A-frag 16x16x16 over h-features (no sigma; h never stored).
// ---------------------------------------------------------------------------
__global__ void prep_kernel(
    const float* __restrict__ cn_w1, const float* __restrict__ cn_w2,
    const float* __restrict__ bn_w1, const float* __restrict__ bn_w2,
    const float* __restrict__ bn_b1, const float* __restrict__ label_emb,
    short* __restrict__ wblob, float* __restrict__ contrib)
{
    const int tid = threadIdx.x;
    for (int idx = tid; idx < 8192; idx += 256) {   // w1 packs (K=128)
        const int e = idx & 7, l = (idx >> 3) & 63, fb = idx >> 9;
        const int kt = fb >> 2, mt = fb & 3;
        const int f_lin = (kt & 1) * 32 + (l >> 4) * 8 + e;  // stored position in row
        const int k = (kt >> 1) * 64 + sigma_(f_lin);        // actual concat feature
        const int n = mt * 16 + (l & 15);
        short h, lo;
        splitbf(cn_w1[k * 64 + n], h, lo);
        wblob[OFF_C1H + idx] = h; wblob[OFF_C1L + idx] = lo;
        splitbf(bn_w1[k * 64 + n], h, lo);
        wblob[OFF_B1H + idx] = h; wblob[OFF_B1L + idx] = lo;
    }
    for (int idx = tid; idx < 4096; idx += 256) {   // w2^T packs (16x16x16 A)
        const int e = idx & 3, l = (idx >> 2) & 63, fb = idx >> 8;
        const int ks = fb >> 2, mt2 = fb & 3;
        const int k = ks * 16 + (l >> 4) * 4 + e;            // h feature
        const int n = mt2 * 16 + (l & 15);                   // output feature
        short h, lo;
        splitbf(cn_w2[k * 64 + n], h, lo);
        wblob[OFF_C2TH + idx] = h; wblob[OFF_C2TL + idx] = lo;
        splitbf(bn_w2[k * 64 + n], h, lo);
        wblob[OFF_B2TH + idx] = h; wblob[OFF_B2TL + idx] = lo;
    }
    if (tid < 128) {                                 // contrib[c][n] = b1[n] + le[c]@bn_w1[128:]
        const int c = tid >> 6, n = tid & 63;
        float s = bn_b1[n];
        for (int kk = 0; kk < 64; ++kk)
            s = fmaf(label_emb[c * 64 + kk], bn_w1[(128 + kk) * 64 + n], s);
        contrib[c * 64 + n] = s;
    }
}

// ---------------------------------------------------------------------------
// Embedding (fp32 vector). Writes e as bf16 hi/lo planes in sigma order.
// ---------------------------------------------------------------------------
__global__ __launch_bounds__(256, 4) void emb_kernel(
    const int* __restrict__ x, const float* __restrict__ y,
    const float* __restrict__ w1, const float* __restrict__ b1,
    const float* __restrict__ w2, const float* __restrict__ b2,
    short* __restrict__ e_hi, short* __restrict__ e_lo, int* __restrict__ v_out)
{
    __shared__ float h_lds[128 * PSTR];
    const int tid = threadIdx.x;
    const int s   = tid & 7;
    const int g   = tid >> 3;
    const int jj0 = s * 8;
    const int i0  = (blockIdx.x * 32 + g) * 4;

    {
        f4 wa0 = LD4(w1 + jj0),      wa1 = LD4(w1 + jj0 + 4);
        f4 wb0 = LD4(w1 + D_ + jj0), wb1 = LD4(w1 + D_ + jj0 + 4);
        f4 bb0 = LD4(b1 + jj0),      bb1 = LD4(b1 + jj0 + 4);
#pragma unroll
        for (int pp = 0; pp < 4; ++pp) {
            const float2 yv = *(const float2*)(y + 2 * (i0 + pp));
            f4 h0, h1;
            h0.x = fmaxf(fmaf(yv.y, wb0.x, fmaf(yv.x, wa0.x, bb0.x)), 0.f);
            h0.y = fmaxf(fmaf(yv.y, wb0.y, fmaf(yv.x, wa0.y, bb0.y)), 0.f);
            h0.z = fmaxf(fmaf(yv.y, wb0.z, fmaf(yv.x, wa0.z, bb0.z)), 0.f);
            h0.w = fmaxf(fmaf(yv.y, wb0.w, fmaf(yv.x, wa0.w, bb0.w)), 0.f);
            h1.x = fmaxf(fmaf(yv.y, wb1.x, fmaf(yv.x, wa1.x, bb1.x)), 0.f);
            h1.y = fmaxf(fmaf(yv.y, wb1.y, fmaf(yv.x, wa1.y, bb1.y)), 0.f);
            h1.z = fmaxf(fmaf(yv.y, wb1.z, fmaf(yv.x, wa1.z, bb1.z)), 0.f);
            h1.w = fmaxf(fmaf(yv.y, wb1.w, fmaf(yv.x, wa1.w, bb1.w)), 0.f);
            float* hp = h_lds + (g * 4 + pp) * PSTR + jj0;
            *(f4*)hp = h0; *(f4*)(hp + 4) = h1;
        }
    }
    __syncthreads();

    float o[4][8];
    {
        f4 b20 = LD4(b2 + jj0), b21 = LD4(b2 + jj0 + 4);
#pragma unroll
        for (int pp = 0; pp < 4; ++pp) {
            o[pp][0]=b20.x; o[pp][1]=b20.y; o[pp][2]=b20.z; o[pp][3]=b20.w;
            o[pp][4]=b21.x; o[pp][5]=b21.y; o[pp][6]=b21.z; o[pp][7]=b21.w;
        }
    }
#pragma unroll 2
    for (int k4 = 0; k4 < 16; ++k4) {
        const f4 x0 = LD4(h_lds + (g * 4 + 0) * PSTR + 4 * k4);
        const f4 x1 = LD4(h_lds + (g * 4 + 1) * PSTR + 4 * k4);
        const f4 x2 = LD4(h_lds + (g * 4 + 2) * PSTR + 4 * k4);
        const f4 x3 = LD4(h_lds + (g * 4 + 3) * PSTR + 4 * k4);
        const float* wk = w2 + (4 * k4) * D_ + jj0;
#pragma unroll
        for (int q = 0; q < 4; ++q) {
            const f4 wa = LD4(wk + q * D_), wb = LD4(wk + q * D_ + 4);
            fma8(o[0], f4c(x0, q), wa, wb);
            fma8(o[1], f4c(x1, q), wa, wb);
            fma8(o[2], f4c(x2, q), wa, wb);
            fma8(o[3], f4c(x3, q), wa, wb);
        }
    }

    const int sp0 = (((jj0 >> 2) & 3) << 4) | (((jj0 >> 4) & 3) << 2);
    const int sp1 = ((((jj0 + 4) >> 2) & 3) << 4) | ((((jj0 + 4) >> 4) & 3) << 2);
#pragma unroll
    for (int pp = 0; pp < 4; ++pp) {
        const size_t rb = (size_t)(i0 + pp) * D_;
        union { short s[8]; uint2 v[2]; } uh, ul;
#pragma unroll
        for (int q = 0; q < 8; ++q) splitbf(o[pp][q], uh.s[q], ul.s[q]);
        *(uint2*)(e_hi + rb + sp0) = uh.v[0];
        *(uint2*)(e_hi + rb + sp1) = uh.v[1];
        *(uint2*)(e_lo + rb + sp0) = ul.v[0];
        *(uint2*)(e_lo + rb + sp1) = ul.v[1];
    }
    if (s < 4) v_out[i0 + s] = x[i0 + s];
}

// ---------------------------------------------------------------------------
// Unified tree stage (all t): weights resident in LDS; swapped-operand MFMA.
// 512 threads = 8 waves x 32 pairs. Grid = 256 blocks.
// L1: C[feat][pair] = W1^T x E^T (16x16x32, 3-term hi/lo).
// L2: O[feat][pair] = W2^T x relu(C) (16x16x16, h lane-local).
// e stored sigma-permuted -> lane's 16 output features are contiguous.
// ---------------------------------------------------------------------------
__global__ __launch_bounds__(512, 2) void stage_kernel(
    const short* __restrict__ e_hi, const short* __restrict__ e_lo,
    const int* __restrict__ v_in,
    short* __restrict__ eo_hi, short* __restrict__ eo_lo, int* __restrict__ v_out,
    const short* __restrict__ wblob,
    const float* __restrict__ cn_b1, const float* __restrict__ cn_b2,
    const float* __restrict__ bn_b2, const float* __restrict__ contrib,
    const float* __restrict__ llr_w, const float* __restrict__ llr_b,
    float* __restrict__ loss_out, float2* __restrict__ pscr,
    int t, int log2Lh)
{
    __shared__ short wlds[WBLOB_SHORTS];   // 96 KB
    const int tid = threadIdx.x;
    {
        const uint4* src = (const uint4*)wblob;
        uint4* dst = (uint4*)wlds;
#pragma unroll
        for (int i = 0; i < 12; ++i)
            dst[tid + i * 512] = src[tid + i * 512];
    }
    __syncthreads();

    const int lane = tid & 63;
    const int pr = lane & 15, kg = lane >> 4;
    const int wid = tid >> 6;
    const int P0 = (blockIdx.x * 8 + wid) * 32;
    const int b  = P0 >> 11;
    const int Lh = 1 << log2Lh;

    int v1s[2], vx[2];
#pragma unroll
    for (int s = 0; s < 2; ++s) {
        const int gp = P0 + s * 16 + pr;
        const int2 vv = *(const int2*)(v_in + 2 * gp);
        v1s[s] = vv.y; vx[s] = (vv.x ^ vv.y) & 1;
    }

    // ---- layer 1 accumulators (row = feature mt*16+kg*4+reg, col = pair pr)
    f32x4 aC[2][4], aB[2][4];
#pragma unroll
    for (int mt = 0; mt < 4; ++mt) {
        const f4 bc = LD4(cn_b1 + mt * 16 + kg * 4);
#pragma unroll
        for (int s = 0; s < 2; ++s) {
            aC[s][mt] = (f32x4){bc.x, bc.y, bc.z, bc.w};
            const f4 cb = LD4(contrib + vx[s] * 64 + mt * 16 + kg * 4);
            aB[s][mt] = (f32x4){cb.x, cb.y, cb.z, cb.w};
        }
    }

#pragma unroll
    for (int kt = 0; kt < 4; ++kt) {
        short8 Eh[2], El[2];
#pragma unroll
        for (int s = 0; s < 2; ++s) {
            const size_t pos = (size_t)(2 * (P0 + s * 16 + pr) + (kt >> 1));
            const int off = (kt & 1) * 32 + kg * 8;
            Eh[s] = *(const short8*)(e_hi + pos * D_ + off);
            El[s] = *(const short8*)(e_lo + pos * D_ + off);
        }
#pragma unroll
        for (int mt = 0; mt < 4; ++mt) {
            const int fo = ((kt * 4 + mt) * 64 + lane) * 8;
            const short8 wh = *(const short8*)(wlds + OFF_C1H + fo);
            const short8 wl = *(const short8*)(wlds + OFF_C1L + fo);
            const short8 uh = *(const short8*)(wlds + OFF_B1H + fo);
            const short8 ul = *(const short8*)(wlds + OFF_B1L + fo);
#pragma unroll
            for (int s = 0; s < 2; ++s) {
                aC[s][mt] = MFMA(wh, Eh[s], aC[s][mt]);
                aC[s][mt] = MFMA(wl, Eh[s], aC[s][mt]);
                aC[s][mt] = MFMA(wh, El[s], aC[s][mt]);
                aB[s][mt] = MFMA(uh, Eh[s], aB[s][mt]);
                aB[s][mt] = MFMA(ul, Eh[s], aB[s][mt]);
                aB[s][mt] = MFMA(uh, El[s], aB[s][mt]);
            }
        }
    }

#pragma unroll
    for (int net = 0; net < 2; ++net) {
        const int w2h_off = net ? OFF_B2TH : OFF_C2TH;
        const int w2l_off = net ? OFF_B2TL : OFF_C2TL;
        const float* __restrict__ b2 = net ? bn_b2 : cn_b2;

        // h = relu(acc): lane-local split into 16x16x16 B-frags
        s4b hh[2][4], hl[2][4];
#pragma unroll
        for (int s = 0; s < 2; ++s)
#pragma unroll
            for (int ks = 0; ks < 4; ++ks) {
                const f32x4 a = net ? aB[s][ks] : aC[s][ks];
#pragma unroll
                for (int e2 = 0; e2 < 4; ++e2) {
                    short sh, sl2;
                    splitbf(fmaxf(a[e2], 0.f), sh, sl2);
                    hh[s][ks][e2] = sh; hl[s][ks][e2] = sl2;
                }
            }

        f32x4 o[2][4];
#pragma unroll
        for (int mt2 = 0; mt2 < 4; ++mt2) {
            const f4 bb = LD4(b2 + mt2 * 16 + kg * 4);
#pragma unroll
            for (int s = 0; s < 2; ++s) o[s][mt2] = (f32x4){bb.x, bb.y, bb.z, bb.w};
        }
#pragma unroll
        for (int ks = 0; ks < 4; ++ks)
#pragma unroll
            for (int mt2 = 0; mt2 < 4; ++mt2) {
                const int fo4 = ((ks * 4 + mt2) * 64 + lane) * 4;
                const s4b wh = *(const s4b*)(wlds + w2h_off + fo4);
                const s4b wl = *(const s4b*)(wlds + w2l_off + fo4);
#pragma unroll
                for (int s = 0; s < 2; ++s) {
                    o[s][mt2] = MFMA16(wh, hh[s][ks], o[s][mt2]);
                    o[s][mt2] = MFMA16(wl, hh[s][ks], o[s][mt2]);
                    o[s][mt2] = MFMA16(wh, hl[s][ks], o[s][mt2]);
                }
            }

#pragma unroll
        for (int s = 0; s < 2; ++s) {
            const int gp = P0 + s * 16 + pr;
            const int P  = gp & 2047;
            const int j  = P & (Lh - 1);
            const int io = 2 * P - j + (net ? Lh : 0);
            const int gout = b * N_ + io;

            // llr head partials + reduce over kg groups
            float z0 = 0.f, z1 = 0.f;
#pragma unroll
            for (int mt2 = 0; mt2 < 4; ++mt2) {
                const int f0 = mt2 * 16 + kg * 4;
                const f4 wA = LD4(llr_w + 2 * f0);
                const f4 wB = LD4(llr_w + 2 * f0 + 4);
                z0 += o[s][mt2][0] * wA.x + o[s][mt2][1] * wA.z +
                      o[s][mt2][2] * wB.x + o[s][mt2][3] * wB.z;
                z1 += o[s][mt2][0] * wA.y + o[s][mt2][1] * wA.w +
                      o[s][mt2][2] * wB.y + o[s][mt2][3] * wB.w;
            }
            z0 += __shfl_xor(z0, 16); z1 += __shfl_xor(z1, 16);
            z0 += __shfl_xor(z0, 32); z1 += __shfl_xor(z1, 32);

            // e_new write: sigma layout -> lane's 16 features contiguous at kg*16
            union { short sv[16]; uint4 v[2]; } ph, pl;
#pragma unroll
            for (int mt2 = 0; mt2 < 4; ++mt2)
#pragma unroll
                for (int e2 = 0; e2 < 4; ++e2) {
                    short sh, sl2;
                    splitbf(o[s][mt2][e2], sh, sl2);
                    ph.sv[mt2 * 4 + e2] = sh; pl.sv[mt2 * 4 + e2] = sl2;
                }
            const size_t eb = (size_t)gout * D_ + kg * 16;
            *(uint4*)(eo_hi + eb)     = ph.v[0];
            *(uint4*)(eo_hi + eb + 8) = ph.v[1];
            *(uint4*)(eo_lo + eb)     = pl.v[0];
            *(uint4*)(eo_lo + eb + 8) = pl.v[1];

            if (kg == 0) {
                v_out[gout] = net ? v1s[s] : vx[s];
                const float zz0 = z0 + llr_b[0], zz1 = z1 + llr_b[1];
                const float m   = fmaxf(zz0, zz1);
                const float ex0 = expf(zz0 - m), ex1 = expf(zz1 - m);
                const float inv = 1.0f / (ex0 + ex1);
                const float p0s = ex0 * inv, p1s = ex1 * inv;
                const float c0  = fminf(fmaxf(p0s, EPS_), 1.0f - EPS_);
                const float c1  = fminf(fmaxf(p1s, EPS_), 1.0f - EPS_);
                const int   lab = net ? (v1s[s] & 1) : vx[s];
                const float loss = -logf(lab ? c1 : c0);
                loss_out[(b * T_ + t) * N_ + io] = loss;
                pscr[(size_t)(b * T_ + t) * N_ + io] = make_float2(p0s, p1s);
            }
        }
    }
}

// ---------------------------------------------------------------------------
// Final: transpose pscr [b][t][io](2) -> pred [b][io][t][2], both copies.
// ---------------------------------------------------------------------------
__global__ __launch_bounds__(256) void pred_epilogue(
    const float2* __restrict__ pscr,
    float* __restrict__ pred1, float* __restrict__ pred2)
{
    const int idx = blockIdx.x * 256 + threadIdx.x;   // b*N + io
    const int b = idx >> 12, io = idx & (N_ - 1);
    float2 v[T_];
#pragma unroll
    for (int t = 0; t < T_; ++t)
        v[t] = pscr[(size_t)(b * T_ + t) * N_ + io];
    float* d1 = pred1 + (size_t)idx * (T_ * 2);
    float* d2 = pred2 + (size_t)idx * (T_ * 2);
#pragma unroll
    for (int q = 0; q < 6; ++q) {
        const f4 w = make_float4(v[2 * q].x, v[2 * q].y, v[2 * q + 1].x, v[2 * q + 1].y);
        *(f4*)(d1 + 4 * q) = w;
        *(f4*)(d2 + 4 * q) = w;
    }
}

// ---------------------------------------------------------------------------
extern "C" void kernel_launch(void* const* d_in, const int* in_sizes, int n_in,
                              void* d_out, int out_size, void* d_ws, size_t ws_size,
                              hipStream_t stream)
{
    const int*   x      = (const int*)  d_in[0];
    const float* y      = (const float*)d_in[1];
    const float* emb_w1 = (const float*)d_in[2];
    const float* emb_b1 = (const float*)d_in[3];
    const float* emb_w2 = (const float*)d_in[4];
    const float* emb_b2 = (const float*)d_in[5];
    const float* cn_w1  = (const float*)d_in[6];
    const float* cn_b1  = (const float*)d_in[7];
    const float* cn_w2  = (const float*)d_in[8];
    const float* cn_b2  = (const float*)d_in[9];
    const float* bn_w1  = (const float*)d_in[10];
    const float* bn_b1  = (const float*)d_in[11];
    const float* bn_w2  = (const float*)d_in[12];
    const float* bn_b2  = (const float*)d_in[13];
    const float* llr_w  = (const float*)d_in[14];
    const float* llr_b  = (const float*)d_in[15];
    const float* label_emb = (const float*)d_in[16];

    float* out      = (float*)d_out;
    float* loss_out = out;
    float* pred1    = out + (size_t)B_ * T_ * N_;
    float* pred2    = pred1 + (size_t)B_ * N_ * T_ * 2;

    const size_t EPLANE = (size_t)B_ * N_ * D_;
    short* eh_a = (short*)d_ws;
    short* el_a = eh_a + EPLANE;
    short* eh_b = el_a + EPLANE;
    short* el_b = eh_b + EPLANE;
    int*   v_a  = (int*)(el_b + EPLANE);
    int*   v_b  = v_a + B_ * N_;
    float2* pscr = (float2*)(v_b + B_ * N_);          // B*T*N float2
    short* wblob = (short*)(pscr + (size_t)B_ * T_ * N_);
    float* contrib = (float*)(wblob + WBLOB_SHORTS);

    prep_kernel<<<1, 256, 0, stream>>>(
        cn_w1, cn_w2, bn_w1, bn_w2, bn_b1, label_emb, wblob, contrib);

    emb_kernel<<<dim3(B_ * N_ / 128), dim3(256), 0, stream>>>(
        x, y, emb_w1, emb_b1, emb_w2, emb_b2, eh_a, el_a, v_a);

    short* ehc = eh_a; short* elc = el_a; short* ehn = eh_b; short* eln = el_b;
    int* vc = v_a; int* vn = v_b;
    for (int t = 0; t < T_; ++t) {
        stage_kernel<<<dim3(B_ * N_ / 2 / 256), dim3(512), 0, stream>>>(
            ehc, elc, vc, ehn, eln, vn, wblob,
            cn_b1, cn_b2, bn_b2, contrib, llr_w, llr_b,
            loss_out, pscr, t, 11 - t);
        short* t1 = ehc; ehc = ehn; ehn = t1;
        short* t2 = elc; elc = eln; eln = t2;
        int* t3 = vc; vc = vn; vn = t3;
    }

    pred_epilogue<<<dim3(B_ * N_ / 256), dim3(256), 0, stream>>>(
        pscr, pred1, pred2);
}

// Round 10
// 266.300 us; speedup vs baseline: 2.3191x; 1.1100x over previous
//
#include <hip/hip_runtime.h>
#include <math.h>

#define B_ 32
#define N_ 4096
#define D_ 64
#define T_ 12
#define EPS_ 1e-7f
#define PSTR 65

typedef float4 f4;
#define LD4(p) (*(const float4*)(p))

typedef __attribute__((ext_vector_type(8))) short short8;
typedef __attribute__((ext_vector_type(4))) short s4b;
typedef __attribute__((ext_vector_type(4))) float f32x4;
#define MFMA(a, b, c)   __builtin_amdgcn_mfma_f32_16x16x32_bf16(a, b, c, 0, 0, 0)
#define MFMA16(a, b, c) __builtin_amdgcn_mfma_f32_16x16x16bf16_1k(a, b, c, 0, 0, 0)

// weight blob LDS offsets (shorts)
#define OFF_C1H 0
#define OFF_C1L 8192
#define OFF_B1H 16384
#define OFF_B1L 24576
#define OFF_C2TH 32768
#define OFF_C2TL 36864
#define OFF_B2TH 40960
#define OFF_B2TL 45056
#define WBLOB_SHORTS 49152

__device__ __forceinline__ float f4c(const float4 v, int q) {
    return q == 0 ? v.x : q == 1 ? v.y : q == 2 ? v.z : v.w;
}
__device__ __forceinline__ void fma8(float (&acc)[8], float a, const float4 w0, const float4 w1) {
    acc[0] = fmaf(a, w0.x, acc[0]); acc[1] = fmaf(a, w0.y, acc[1]);
    acc[2] = fmaf(a, w0.z, acc[2]); acc[3] = fmaf(a, w0.w, acc[3]);
    acc[4] = fmaf(a, w1.x, acc[4]); acc[5] = fmaf(a, w1.y, acc[5]);
    acc[6] = fmaf(a, w1.z, acc[6]); acc[7] = fmaf(a, w1.w, acc[7]);
}

__device__ __forceinline__ void splitbf(float a, short& h, short& l) {
    unsigned x = __float_as_uint(a);
    h = (short)(x >> 16);
    float r = a - __uint_as_float(x & 0xffff0000u);
    l = (short)(__float_as_uint(r) >> 16);
}
__device__ __forceinline__ unsigned packsplit(float a) {
    unsigned x = __float_as_uint(a);
    unsigned hib = x & 0xffff0000u;
    float r = a - __uint_as_float(hib);
    return (x >> 16) | (__float_as_uint(r) & 0xffff0000u);
}

// sigma: involutive feature permutation for e-storage (swap bits[5:4]<->[3:2])
__device__ __forceinline__ int sigma_(int f) {
    return (((f >> 2) & 3) << 4) | (((f >> 4) & 3) << 2) | (f & 3);
}

// ---------------------------------------------------------------------------
// Prep: pack weights (hi/lo planes) into one contiguous blob + bn contrib.
// ---------------------------------------------------------------------------
__global__ void prep_kernel(
    const float* __restrict__ cn_w1, const float* __restrict__ cn_w2,
    const float* __restrict__ bn_w1, const float* __restrict__ bn_w2,
    const float* __restrict__ bn_b1, const float* __restrict__ label_emb,
    short* __restrict__ wblob, float* __restrict__ contrib)
{
    const int tid = threadIdx.x;
    for (int idx = tid; idx < 8192; idx += 256) {   // w1 packs (K=128)
        const int e = idx & 7, l = (idx >> 3) & 63, fb = idx >> 9;
        const int kt = fb >> 2, mt = fb & 3;
        const int f_lin = (kt & 1) * 32 + (l >> 4) * 8 + e;
        const int k = (kt >> 1) * 64 + sigma_(f_lin);
        const int n = mt * 16 + (l & 15);
        short h, lo;
        splitbf(cn_w1[k * 64 + n], h, lo);
        wblob[OFF_C1H + idx] = h; wblob[OFF_C1L + idx] = lo;
        splitbf(bn_w1[k * 64 + n], h, lo);
        wblob[OFF_B1H + idx] = h; wblob[OFF_B1L + idx] = lo;
    }
    for (int idx = tid; idx < 4096; idx += 256) {   // w2^T packs (16x16x16 A)
        const int e = idx & 3, l = (idx >> 2) & 63, fb = idx >> 8;
        const int ks = fb >> 2, mt2 = fb & 3;
        const int k = ks * 16 + (l >> 4) * 4 + e;
        const int n = mt2 * 16 + (l & 15);
        short h, lo;
        splitbf(cn_w2[k * 64 + n], h, lo);
        wblob[OFF_C2TH + idx] = h; wblob[OFF_C2TL + idx] = lo;
        splitbf(bn_w2[k * 64 + n], h, lo);
        wblob[OFF_B2TH + idx] = h; wblob[OFF_B2TL + idx] = lo;
    }
    if (tid < 128) {
        const int c = tid >> 6, n = tid & 63;
        float s = bn_b1[n];
        for (int kk = 0; kk < 64; ++kk)
            s = fmaf(label_emb[c * 64 + kk], bn_w1[(128 + kk) * 64 + n], s);
        contrib[c * 64 + n] = s;
    }
}

// ---------------------------------------------------------------------------
// Embedding (fp32 vector). Writes e as bf16 hi/lo planes in sigma order.
// ---------------------------------------------------------------------------
__global__ __launch_bounds__(256, 4) void emb_kernel(
    const int* __restrict__ x, const float* __restrict__ y,
    const float* __restrict__ w1, const float* __restrict__ b1,
    const float* __restrict__ w2, const float* __restrict__ b2,
    short* __restrict__ e_hi, short* __restrict__ e_lo, int* __restrict__ v_out)
{
    __shared__ float h_lds[128 * PSTR];
    const int tid = threadIdx.x;
    const int s   = tid & 7;
    const int g   = tid >> 3;
    const int jj0 = s * 8;
    const int i0  = (blockIdx.x * 32 + g) * 4;

    {
        f4 wa0 = LD4(w1 + jj0),      wa1 = LD4(w1 + jj0 + 4);
        f4 wb0 = LD4(w1 + D_ + jj0), wb1 = LD4(w1 + D_ + jj0 + 4);
        f4 bb0 = LD4(b1 + jj0),      bb1 = LD4(b1 + jj0 + 4);
#pragma unroll
        for (int pp = 0; pp < 4; ++pp) {
            const float2 yv = *(const float2*)(y + 2 * (i0 + pp));
            f4 h0, h1;
            h0.x = fmaxf(fmaf(yv.y, wb0.x, fmaf(yv.x, wa0.x, bb0.x)), 0.f);
            h0.y = fmaxf(fmaf(yv.y, wb0.y, fmaf(yv.x, wa0.y, bb0.y)), 0.f);
            h0.z = fmaxf(fmaf(yv.y, wb0.z, fmaf(yv.x, wa0.z, bb0.z)), 0.f);
            h0.w = fmaxf(fmaf(yv.y, wb0.w, fmaf(yv.x, wa0.w, bb0.w)), 0.f);
            h1.x = fmaxf(fmaf(yv.y, wb1.x, fmaf(yv.x, wa1.x, bb1.x)), 0.f);
            h1.y = fmaxf(fmaf(yv.y, wb1.y, fmaf(yv.x, wa1.y, bb1.y)), 0.f);
            h1.z = fmaxf(fmaf(yv.y, wb1.z, fmaf(yv.x, wa1.z, bb1.z)), 0.f);
            h1.w = fmaxf(fmaf(yv.y, wb1.w, fmaf(yv.x, wa1.w, bb1.w)), 0.f);
            float* hp = h_lds + (g * 4 + pp) * PSTR + jj0;
            *(f4*)hp = h0; *(f4*)(hp + 4) = h1;
        }
    }
    __syncthreads();

    float o[4][8];
    {
        f4 b20 = LD4(b2 + jj0), b21 = LD4(b2 + jj0 + 4);
#pragma unroll
        for (int pp = 0; pp < 4; ++pp) {
            o[pp][0]=b20.x; o[pp][1]=b20.y; o[pp][2]=b20.z; o[pp][3]=b20.w;
            o[pp][4]=b21.x; o[pp][5]=b21.y; o[pp][6]=b21.z; o[pp][7]=b21.w;
        }
    }
#pragma unroll 2
    for (int k4 = 0; k4 < 16; ++k4) {
        const f4 x0 = LD4(h_lds + (g * 4 + 0) * PSTR + 4 * k4);
        const f4 x1 = LD4(h_lds + (g * 4 + 1) * PSTR + 4 * k4);
        const f4 x2 = LD4(h_lds + (g * 4 + 2) * PSTR + 4 * k4);
        const f4 x3 = LD4(h_lds + (g * 4 + 3) * PSTR + 4 * k4);
        const float* wk = w2 + (4 * k4) * D_ + jj0;
#pragma unroll
        for (int q = 0; q < 4; ++q) {
            const f4 wa = LD4(wk + q * D_), wb = LD4(wk + q * D_ + 4);
            fma8(o[0], f4c(x0, q), wa, wb);
            fma8(o[1], f4c(x1, q), wa, wb);
            fma8(o[2], f4c(x2, q), wa, wb);
            fma8(o[3], f4c(x3, q), wa, wb);
        }
    }

    const int sp0 = (((jj0 >> 2) & 3) << 4) | (((jj0 >> 4) & 3) << 2);
    const int sp1 = ((((jj0 + 4) >> 2) & 3) << 4) | ((((jj0 + 4) >> 4) & 3) << 2);
#pragma unroll
    for (int pp = 0; pp < 4; ++pp) {
        const size_t rb = (size_t)(i0 + pp) * D_;
        union { short s[8]; uint2 v[2]; } uh, ul;
#pragma unroll
        for (int q = 0; q < 8; ++q) splitbf(o[pp][q], uh.s[q], ul.s[q]);
        *(uint2*)(e_hi + rb + sp0) = uh.v[0];
        *(uint2*)(e_hi + rb + sp1) = uh.v[1];
        *(uint2*)(e_lo + rb + sp0) = ul.v[0];
        *(uint2*)(e_lo + rb + sp1) = ul.v[1];
    }
    if (s < 4) v_out[i0 + s] = x[i0 + s];
}

// ---------------------------------------------------------------------------
// Global tree stage (t = 0..4): weights in LDS; swapped-operand MFMA.
// ---------------------------------------------------------------------------
__global__ __launch_bounds__(512, 2) void stage_kernel(
    const short* __restrict__ e_hi, const short* __restrict__ e_lo,
    const int* __restrict__ v_in,
    short* __restrict__ eo_hi, short* __restrict__ eo_lo, int* __restrict__ v_out,
    const short* __restrict__ wblob,
    const float* __restrict__ cn_b1, const float* __restrict__ cn_b2,
    const float* __restrict__ bn_b2, const float* __restrict__ contrib,
    const float* __restrict__ llr_w, const float* __restrict__ llr_b,
    float* __restrict__ loss_out, float2* __restrict__ pscr,
    int t, int log2Lh)
{
    __shared__ short wlds[WBLOB_SHORTS];   // 96 KB
    const int tid = threadIdx.x;
    {
        const uint4* src = (const uint4*)wblob;
        uint4* dst = (uint4*)wlds;
#pragma unroll
        for (int i = 0; i < 12; ++i)
            dst[tid + i * 512] = src[tid + i * 512];
    }
    __syncthreads();

    const int lane = tid & 63;
    const int pr = lane & 15, kg = lane >> 4;
    const int wid = tid >> 6;
    const int P0 = (blockIdx.x * 8 + wid) * 32;
    const int b  = P0 >> 11;
    const int Lh = 1 << log2Lh;

    int v1s[2], vx[2];
#pragma unroll
    for (int s = 0; s < 2; ++s) {
        const int gp = P0 + s * 16 + pr;
        const int2 vv = *(const int2*)(v_in + 2 * gp);
        v1s[s] = vv.y; vx[s] = (vv.x ^ vv.y) & 1;
    }

    f32x4 aC[2][4], aB[2][4];
#pragma unroll
    for (int mt = 0; mt < 4; ++mt) {
        const f4 bc = LD4(cn_b1 + mt * 16 + kg * 4);
#pragma unroll
        for (int s = 0; s < 2; ++s) {
            aC[s][mt] = (f32x4){bc.x, bc.y, bc.z, bc.w};
            const f4 cb = LD4(contrib + vx[s] * 64 + mt * 16 + kg * 4);
            aB[s][mt] = (f32x4){cb.x, cb.y, cb.z, cb.w};
        }
    }

#pragma unroll
    for (int kt = 0; kt < 4; ++kt) {
        short8 Eh[2], El[2];
#pragma unroll
        for (int s = 0; s < 2; ++s) {
            const size_t pos = (size_t)(2 * (P0 + s * 16 + pr) + (kt >> 1));
            const int off = (kt & 1) * 32 + kg * 8;
            Eh[s] = *(const short8*)(e_hi + pos * D_ + off);
            El[s] = *(const short8*)(e_lo + pos * D_ + off);
        }
#pragma unroll
        for (int mt = 0; mt < 4; ++mt) {
            const int fo = ((kt * 4 + mt) * 64 + lane) * 8;
            const short8 wh = *(const short8*)(wlds + OFF_C1H + fo);
            const short8 wl = *(const short8*)(wlds + OFF_C1L + fo);
            const short8 uh = *(const short8*)(wlds + OFF_B1H + fo);
            const short8 ul = *(const short8*)(wlds + OFF_B1L + fo);
#pragma unroll
            for (int s = 0; s < 2; ++s) {
                aC[s][mt] = MFMA(wh, Eh[s], aC[s][mt]);
                aC[s][mt] = MFMA(wl, Eh[s], aC[s][mt]);
                aC[s][mt] = MFMA(wh, El[s], aC[s][mt]);
                aB[s][mt] = MFMA(uh, Eh[s], aB[s][mt]);
                aB[s][mt] = MFMA(ul, Eh[s], aB[s][mt]);
                aB[s][mt] = MFMA(uh, El[s], aB[s][mt]);
            }
        }
    }

#pragma unroll
    for (int net = 0; net < 2; ++net) {
        const int w2h_off = net ? OFF_B2TH : OFF_C2TH;
        const int w2l_off = net ? OFF_B2TL : OFF_C2TL;
        const float* __restrict__ b2 = net ? bn_b2 : cn_b2;

        s4b hh[2][4], hl[2][4];
#pragma unroll
        for (int s = 0; s < 2; ++s)
#pragma unroll
            for (int ks = 0; ks < 4; ++ks) {
                const f32x4 a = net ? aB[s][ks] : aC[s][ks];
#pragma unroll
                for (int e2 = 0; e2 < 4; ++e2) {
                    short sh, sl2;
                    splitbf(fmaxf(a[e2], 0.f), sh, sl2);
                    hh[s][ks][e2] = sh; hl[s][ks][e2] = sl2;
                }
            }

        f32x4 o[2][4];
#pragma unroll
        for (int mt2 = 0; mt2 < 4; ++mt2) {
            const f4 bb = LD4(b2 + mt2 * 16 + kg * 4);
#pragma unroll
            for (int s = 0; s < 2; ++s) o[s][mt2] = (f32x4){bb.x, bb.y, bb.z, bb.w};
        }
#pragma unroll
        for (int ks = 0; ks < 4; ++ks)
#pragma unroll
            for (int mt2 = 0; mt2 < 4; ++mt2) {
                const int fo4 = ((ks * 4 + mt2) * 64 + lane) * 4;
                const s4b wh = *(const s4b*)(wlds + w2h_off + fo4);
                const s4b wl = *(const s4b*)(wlds + w2l_off + fo4);
#pragma unroll
                for (int s = 0; s < 2; ++s) {
                    o[s][mt2] = MFMA16(wh, hh[s][ks], o[s][mt2]);
                    o[s][mt2] = MFMA16(wl, hh[s][ks], o[s][mt2]);
                    o[s][mt2] = MFMA16(wh, hl[s][ks], o[s][mt2]);
                }
            }

#pragma unroll
        for (int s = 0; s < 2; ++s) {
            const int gp = P0 + s * 16 + pr;
            const int P  = gp & 2047;
            const int j  = P & (Lh - 1);
            const int io = 2 * P - j + (net ? Lh : 0);
            const int gout = b * N_ + io;

            float z0 = 0.f, z1 = 0.f;
#pragma unroll
            for (int mt2 = 0; mt2 < 4; ++mt2) {
                const int f0 = mt2 * 16 + kg * 4;
                const f4 wA = LD4(llr_w + 2 * f0);
                const f4 wB = LD4(llr_w + 2 * f0 + 4);
                z0 += o[s][mt2][0] * wA.x + o[s][mt2][1] * wA.z +
                      o[s][mt2][2] * wB.x + o[s][mt2][3] * wB.z;
                z1 += o[s][mt2][0] * wA.y + o[s][mt2][1] * wA.w +
                      o[s][mt2][2] * wB.y + o[s][mt2][3] * wB.w;
            }
            z0 += __shfl_xor(z0, 16); z1 += __shfl_xor(z1, 16);
            z0 += __shfl_xor(z0, 32); z1 += __shfl_xor(z1, 32);

            union { short sv[16]; uint4 v[2]; } ph, pl;
#pragma unroll
            for (int mt2 = 0; mt2 < 4; ++mt2)
#pragma unroll
                for (int e2 = 0; e2 < 4; ++e2) {
                    short sh, sl2;
                    splitbf(o[s][mt2][e2], sh, sl2);
                    ph.sv[mt2 * 4 + e2] = sh; pl.sv[mt2 * 4 + e2] = sl2;
                }
            const size_t eb = (size_t)gout * D_ + kg * 16;
            *(uint4*)(eo_hi + eb)     = ph.v[0];
            *(uint4*)(eo_hi + eb + 8) = ph.v[1];
            *(uint4*)(eo_lo + eb)     = pl.v[0];
            *(uint4*)(eo_lo + eb + 8) = pl.v[1];

            if (kg == 0) {
                v_out[gout] = net ? v1s[s] : vx[s];
                const float zz0 = z0 + llr_b[0], zz1 = z1 + llr_b[1];
                const float m   = fmaxf(zz0, zz1);
                const float ex0 = expf(zz0 - m), ex1 = expf(zz1 - m);
                const float inv = 1.0f / (ex0 + ex1);
                const float p0s = ex0 * inv, p1s = ex1 * inv;
                const float c0  = fminf(fmaxf(p0s, EPS_), 1.0f - EPS_);
                const float c1  = fminf(fmaxf(p1s, EPS_), 1.0f - EPS_);
                const int   lab = net ? (v1s[s] & 1) : vx[s];
                const float loss = -logf(lab ? c1 : c0);
                loss_out[(b * T_ + t) * N_ + io] = loss;
                pscr[(size_t)(b * T_ + t) * N_ + io] = make_float2(p0s, p1s);
            }
        }
    }
}

// ---------------------------------------------------------------------------
// Fused tail (t = 5..11): weights (96KB) + 128-row e-chunk (34.8KB) in LDS.
// 1024 blocks x 256 threads (4 waves x 16 pairs). Same arithmetic as
// stage_kernel (bit-identical results); e never touches global inside loop.
// ---------------------------------------------------------------------------
__global__ __launch_bounds__(256, 1) void fused_tail(
    const short* __restrict__ e_hi, const short* __restrict__ e_lo,
    const int* __restrict__ v_in,
    const short* __restrict__ wblob,
    const float* __restrict__ cn_b1, const float* __restrict__ cn_b2,
    const float* __restrict__ bn_b2, const float* __restrict__ contrib,
    const float* __restrict__ llr_w, const float* __restrict__ llr_b,
    float* __restrict__ loss_out, float2* __restrict__ pscr)
{
    __shared__ short wlds[WBLOB_SHORTS];       // 96 KB
    __shared__ unsigned e_lds[128 * 68];       // 34816 B, packed hi|lo<<16
    __shared__ int v_lds[128];
    const int tid = threadIdx.x;
    {
        const uint4* src = (const uint4*)wblob;
        uint4* dst = (uint4*)wlds;
#pragma unroll 4
        for (int i = 0; i < 24; ++i)
            dst[tid + i * 256] = src[tid + i * 256];
    }
    const int b = blockIdx.x >> 5, ch = blockIdx.x & 31;
    const int base_row = b * N_ + ch * 128;
    {
        const int r = tid >> 1, half = tid & 1;
        const size_t g = (size_t)(base_row + r) * D_ + half * 32;
        const short8* hp = (const short8*)(e_hi + g);
        const short8* lp = (const short8*)(e_lo + g);
        unsigned* d = &e_lds[r * 68 + half * 32];
#pragma unroll
        for (int q = 0; q < 4; ++q) {
            const short8 h8 = hp[q];
            const short8 l8 = lp[q];
            unsigned u[8];
#pragma unroll
            for (int j2 = 0; j2 < 8; ++j2)
                u[j2] = ((unsigned)(unsigned short)h8[j2]) |
                        (((unsigned)(unsigned short)l8[j2]) << 16);
            *(uint4*)(d + 8 * q)     = make_uint4(u[0], u[1], u[2], u[3]);
            *(uint4*)(d + 8 * q + 4) = make_uint4(u[4], u[5], u[6], u[7]);
        }
        if (tid < 128) v_lds[tid] = v_in[base_row + tid];
    }
    __syncthreads();

    const int lane = tid & 63;
    const int pr = lane & 15, kg = lane >> 4;
    const int p = (tid >> 6) * 16 + pr;      // local pair 0..63

    int Lh = 64;
#pragma unroll 1
    for (int t = 5; t < 12; ++t, Lh >>= 1) {
        const int v0 = v_lds[2 * p], v1 = v_lds[2 * p + 1];
        const int vx = (v0 ^ v1) & 1;

        f32x4 aC[4], aB[4];
#pragma unroll
        for (int mt = 0; mt < 4; ++mt) {
            const f4 bc = LD4(cn_b1 + mt * 16 + kg * 4);
            aC[mt] = (f32x4){bc.x, bc.y, bc.z, bc.w};
            const f4 cb = LD4(contrib + vx * 64 + mt * 16 + kg * 4);
            aB[mt] = (f32x4){cb.x, cb.y, cb.z, cb.w};
        }

#pragma unroll
        for (int kt = 0; kt < 4; ++kt) {
            const unsigned* src = &e_lds[(2 * p + (kt >> 1)) * 68 + (kt & 1) * 32 + kg * 8];
            unsigned xx[8];
            *(uint4*)&xx[0] = *(const uint4*)src;
            *(uint4*)&xx[4] = *(const uint4*)(src + 4);
            union { short8 v; unsigned u[4]; } H, L;
#pragma unroll
            for (int j2 = 0; j2 < 4; ++j2) {
                H.u[j2] = (xx[2 * j2] & 0xffffu) | (xx[2 * j2 + 1] << 16);
                L.u[j2] = (xx[2 * j2] >> 16) | (xx[2 * j2 + 1] & 0xffff0000u);
            }
            const short8 Eh = H.v, El = L.v;
#pragma unroll
            for (int mt = 0; mt < 4; ++mt) {
                const int fo = ((kt * 4 + mt) * 64 + lane) * 8;
                const short8 wh = *(const short8*)(wlds + OFF_C1H + fo);
                const short8 wl = *(const short8*)(wlds + OFF_C1L + fo);
                const short8 uh = *(const short8*)(wlds + OFF_B1H + fo);
                const short8 ul = *(const short8*)(wlds + OFF_B1L + fo);
                aC[mt] = MFMA(wh, Eh, aC[mt]);
                aC[mt] = MFMA(wl, Eh, aC[mt]);
                aC[mt] = MFMA(wh, El, aC[mt]);
                aB[mt] = MFMA(uh, Eh, aB[mt]);
                aB[mt] = MFMA(ul, Eh, aB[mt]);
                aB[mt] = MFMA(uh, El, aB[mt]);
            }
        }

        uint4 pk[2][4];
        int iolA[2], vnewA[2];
#pragma unroll
        for (int net = 0; net < 2; ++net) {
            const int w2h_off = net ? OFF_B2TH : OFF_C2TH;
            const int w2l_off = net ? OFF_B2TL : OFF_C2TL;
            const float* __restrict__ b2 = net ? bn_b2 : cn_b2;

            s4b hh[4], hl[4];
#pragma unroll
            for (int ks = 0; ks < 4; ++ks) {
                const f32x4 a = net ? aB[ks] : aC[ks];
#pragma unroll
                for (int e2 = 0; e2 < 4; ++e2) {
                    short sh, sl2;
                    splitbf(fmaxf(a[e2], 0.f), sh, sl2);
                    hh[ks][e2] = sh; hl[ks][e2] = sl2;
                }
            }

            f32x4 o[4];
#pragma unroll
            for (int mt2 = 0; mt2 < 4; ++mt2) {
                const f4 bb = LD4(b2 + mt2 * 16 + kg * 4);
                o[mt2] = (f32x4){bb.x, bb.y, bb.z, bb.w};
            }
#pragma unroll
            for (int ks = 0; ks < 4; ++ks)
#pragma unroll
                for (int mt2 = 0; mt2 < 4; ++mt2) {
                    const int fo4 = ((ks * 4 + mt2) * 64 + lane) * 4;
                    const s4b wh = *(const s4b*)(wlds + w2h_off + fo4);
                    const s4b wl = *(const s4b*)(wlds + w2l_off + fo4);
                    o[mt2] = MFMA16(wh, hh[ks], o[mt2]);
                    o[mt2] = MFMA16(wl, hh[ks], o[mt2]);
                    o[mt2] = MFMA16(wh, hl[ks], o[mt2]);
                }

            const int j = p & (Lh - 1);
            const int iol = 2 * p - j + (net ? Lh : 0);
            iolA[net] = iol;
            vnewA[net] = net ? v1 : vx;

            float z0 = 0.f, z1 = 0.f;
#pragma unroll
            for (int mt2 = 0; mt2 < 4; ++mt2) {
                union { short sv[4]; uint2 uv; } qh, ql;
#pragma unroll
                for (int e2 = 0; e2 < 4; ++e2) {
                    short sh, sl2;
                    splitbf(o[mt2][e2], sh, sl2);
                    qh.sv[e2] = sh; ql.sv[e2] = sl2;
                }
                pk[net][mt2] = make_uint4(
                    ((unsigned)(unsigned short)qh.sv[0]) | (((unsigned)(unsigned short)ql.sv[0]) << 16),
                    ((unsigned)(unsigned short)qh.sv[1]) | (((unsigned)(unsigned short)ql.sv[1]) << 16),
                    ((unsigned)(unsigned short)qh.sv[2]) | (((unsigned)(unsigned short)ql.sv[2]) << 16),
                    ((unsigned)(unsigned short)qh.sv[3]) | (((unsigned)(unsigned short)ql.sv[3]) << 16));
                const int f0 = mt2 * 16 + kg * 4;
                const f4 wA = LD4(llr_w + 2 * f0);
                const f4 wB = LD4(llr_w + 2 * f0 + 4);
                z0 += o[mt2][0] * wA.x + o[mt2][1] * wA.z +
                      o[mt2][2] * wB.x + o[mt2][3] * wB.z;
                z1 += o[mt2][0] * wA.y + o[mt2][1] * wA.w +
                      o[mt2][2] * wB.y + o[mt2][3] * wB.w;
            }
            z0 += __shfl_xor(z0, 16); z1 += __shfl_xor(z1, 16);
            z0 += __shfl_xor(z0, 32); z1 += __shfl_xor(z1, 32);

            if (kg == 0) {
                const int io = ch * 128 + iol;
                const float zz0 = z0 + llr_b[0], zz1 = z1 + llr_b[1];
                const float m   = fmaxf(zz0, zz1);
                const float ex0 = expf(zz0 - m), ex1 = expf(zz1 - m);
                const float inv = 1.0f / (ex0 + ex1);
                const float p0s = ex0 * inv, p1s = ex1 * inv;
                const float c0  = fminf(fmaxf(p0s, EPS_), 1.0f - EPS_);
                const float c1  = fminf(fmaxf(p1s, EPS_), 1.0f - EPS_);
                const int   lab = net ? (v1 & 1) : vx;
                const float loss = -logf(lab ? c1 : c0);
                loss_out[(b * T_ + t) * N_ + io] = loss;
                pscr[(size_t)(b * T_ + t) * N_ + io] = make_float2(p0s, p1s);
            }
        }
        __syncthreads();   // all e_lds/v_lds reads done

#pragma unroll
        for (int net = 0; net < 2; ++net) {
            unsigned* d = &e_lds[iolA[net] * 68 + kg * 16];
            *(uint4*)d        = pk[net][0];
            *(uint4*)(d + 4)  = pk[net][1];
            *(uint4*)(d + 8)  = pk[net][2];
            *(uint4*)(d + 12) = pk[net][3];
            if (kg == 0) v_lds[iolA[net]] = vnewA[net];
        }
        __syncthreads();   // writes visible for next stage
    }
}

// ---------------------------------------------------------------------------
// Final: transpose pscr [b][t][io](2) -> pred [b][io][t][2], both copies.
// ---------------------------------------------------------------------------
__global__ __launch_bounds__(256) void pred_epilogue(
    const float2* __restrict__ pscr,
    float* __restrict__ pred1, float* __restrict__ pred2)
{
    const int idx = blockIdx.x * 256 + threadIdx.x;   // b*N + io
    const int b = idx >> 12, io = idx & (N_ - 1);
    float2 v[T_];
#pragma unroll
    for (int t = 0; t < T_; ++t)
        v[t] = pscr[(size_t)(b * T_ + t) * N_ + io];
    float* d1 = pred1 + (size_t)idx * (T_ * 2);
    float* d2 = pred2 + (size_t)idx * (T_ * 2);
#pragma unroll
    for (int q = 0; q < 6; ++q) {
        const f4 w = make_float4(v[2 * q].x, v[2 * q].y, v[2 * q + 1].x, v[2 * q + 1].y);
        *(f4*)(d1 + 4 * q) = w;
        *(f4*)(d2 + 4 * q) = w;
    }
}

// ---------------------------------------------------------------------------
extern "C" void kernel_launch(void* const* d_in, const int* in_sizes, int n_in,
                              void* d_out, int out_size, void* d_ws, size_t ws_size,
                              hipStream_t stream)
{
    const int*   x      = (const int*)  d_in[0];
    const float* y      = (const float*)d_in[1];
    const float* emb_w1 = (const float*)d_in[2];
    const float* emb_b1 = (const float*)d_in[3];
    const float* emb_w2 = (const float*)d_in[4];
    const float* emb_b2 = (const float*)d_in[5];
    const float* cn_w1  = (const float*)d_in[6];
    const float* cn_b1  = (const float*)d_in[7];
    const float* cn_w2  = (const float*)d_in[8];
    const float* cn_b2  = (const float*)d_in[9];
    const float* bn_w1  = (const float*)d_in[10];
    const float* bn_b1  = (const float*)d_in[11];
    const float* bn_w2  = (const float*)d_in[12];
    const float* bn_b2  = (const float*)d_in[13];
    const float* llr_w  = (const float*)d_in[14];
    const float* llr_b  = (const float*)d_in[15];
    const float* label_emb = (const float*)d_in[16];

    float* out      = (float*)d_out;
    float* loss_out = out;
    float* pred1    = out + (size_t)B_ * T_ * N_;
    float* pred2    = pred1 + (size_t)B_ * N_ * T_ * 2;

    const size_t EPLANE = (size_t)B_ * N_ * D_;
    short* eh_a = (short*)d_ws;
    short* el_a = eh_a + EPLANE;
    short* eh_b = el_a + EPLANE;
    short* el_b = eh_b + EPLANE;
    int*   v_a  = (int*)(el_b + EPLANE);
    int*   v_b  = v_a + B_ * N_;
    float2* pscr = (float2*)(v_b + B_ * N_);
    short* wblob = (short*)(pscr + (size_t)B_ * T_ * N_);
    float* contrib = (float*)(wblob + WBLOB_SHORTS);

    prep_kernel<<<1, 256, 0, stream>>>(
        cn_w1, cn_w2, bn_w1, bn_w2, bn_b1, label_emb, wblob, contrib);

    emb_kernel<<<dim3(B_ * N_ / 128), dim3(256), 0, stream>>>(
        x, y, emb_w1, emb_b1, emb_w2, emb_b2, eh_a, el_a, v_a);

    short* ehc = eh_a; short* elc = el_a; short* ehn = eh_b; short* eln = el_b;
    int* vc = v_a; int* vn = v_b;
    for (int t = 0; t < 5; ++t) {
        stage_kernel<<<dim3(B_ * N_ / 2 / 256), dim3(512), 0, stream>>>(
            ehc, elc, vc, ehn, eln, vn, wblob,
            cn_b1, cn_b2, bn_b2, contrib, llr_w, llr_b,
            loss_out, pscr, t, 11 - t);
        short* t1 = ehc; ehc = ehn; ehn = t1;
        short* t2 = elc; elc = eln; eln = t2;
        int* t3 = vc; vc = vn; vn = t3;
    }

    fused_tail<<<dim3(1024), dim3(256), 0, stream>>>(
        ehc, elc, vc, wblob,
        cn_b1, cn_b2, bn_b2, contrib, llr_w, llr_b,
        loss_out, pscr);

    pred_epilogue<<<dim3(B_ * N_ / 256), dim3(256), 0, stream>>>(
        pscr, pred1, pred2);
}

// Round 11
// 245.151 us; speedup vs baseline: 2.5191x; 1.0863x over previous
//
#include <hip/hip_runtime.h>
#include <math.h>

#define B_ 32
#define N_ 4096
#define D_ 64
#define T_ 12
#define EPS_ 1e-7f
#define PSTR 65
#define ESTR 72   // e_lds row stride (u32): 2-row step = 144 -> 2-way banks (free)

typedef float4 f4;
#define LD4(p) (*(const float4*)(p))

typedef __attribute__((ext_vector_type(8))) short short8;
typedef __attribute__((ext_vector_type(4))) short s4b;
typedef __attribute__((ext_vector_type(4))) float f32x4;
#define MFMA(a, b, c)   __builtin_amdgcn_mfma_f32_16x16x32_bf16(a, b, c, 0, 0, 0)
#define MFMA16(a, b, c) __builtin_amdgcn_mfma_f32_16x16x16bf16_1k(a, b, c, 0, 0, 0)

// weight blob LDS offsets (shorts)
#define OFF_C1H 0
#define OFF_C1L 8192
#define OFF_B1H 16384
#define OFF_B1L 24576
#define OFF_C2TH 32768
#define OFF_C2TL 36864
#define OFF_B2TH 40960
#define OFF_B2TL 45056
#define WBLOB_SHORTS 49152

__device__ __forceinline__ float f4c(const float4 v, int q) {
    return q == 0 ? v.x : q == 1 ? v.y : q == 2 ? v.z : v.w;
}
__device__ __forceinline__ void fma8(float (&acc)[8], float a, const float4 w0, const float4 w1) {
    acc[0] = fmaf(a, w0.x, acc[0]); acc[1] = fmaf(a, w0.y, acc[1]);
    acc[2] = fmaf(a, w0.z, acc[2]); acc[3] = fmaf(a, w0.w, acc[3]);
    acc[4] = fmaf(a, w1.x, acc[4]); acc[5] = fmaf(a, w1.y, acc[5]);
    acc[6] = fmaf(a, w1.z, acc[6]); acc[7] = fmaf(a, w1.w, acc[7]);
}

__device__ __forceinline__ void splitbf(float a, short& h, short& l) {
    unsigned x = __float_as_uint(a);
    h = (short)(x >> 16);
    float r = a - __uint_as_float(x & 0xffff0000u);
    l = (short)(__float_as_uint(r) >> 16);
}

// sigma: involutive feature permutation for e-storage (swap bits[5:4]<->[3:2])
__device__ __forceinline__ int sigma_(int f) {
    return (((f >> 2) & 3) << 4) | (((f >> 4) & 3) << 2) | (f & 3);
}

// ---------------------------------------------------------------------------
// Prep: pack weights (hi/lo planes) into one contiguous blob + bn contrib.
// ---------------------------------------------------------------------------
__global__ void prep_kernel(
    const float* __restrict__ cn_w1, const float* __restrict__ cn_w2,
    const float* __restrict__ bn_w1, const float* __restrict__ bn_w2,
    const float* __restrict__ bn_b1, const float* __restrict__ label_emb,
    short* __restrict__ wblob, float* __restrict__ contrib)
{
    const int tid = threadIdx.x;
    for (int idx = tid; idx < 8192; idx += 256) {   // w1 packs (K=128)
        const int e = idx & 7, l = (idx >> 3) & 63, fb = idx >> 9;
        const int kt = fb >> 2, mt = fb & 3;
        const int f_lin = (kt & 1) * 32 + (l >> 4) * 8 + e;
        const int k = (kt >> 1) * 64 + sigma_(f_lin);
        const int n = mt * 16 + (l & 15);
        short h, lo;
        splitbf(cn_w1[k * 64 + n], h, lo);
        wblob[OFF_C1H + idx] = h; wblob[OFF_C1L + idx] = lo;
        splitbf(bn_w1[k * 64 + n], h, lo);
        wblob[OFF_B1H + idx] = h; wblob[OFF_B1L + idx] = lo;
    }
    for (int idx = tid; idx < 4096; idx += 256) {   // w2^T packs (16x16x16 A)
        const int e = idx & 3, l = (idx >> 2) & 63, fb = idx >> 8;
        const int ks = fb >> 2, mt2 = fb & 3;
        const int k = ks * 16 + (l >> 4) * 4 + e;
        const int n = mt2 * 16 + (l & 15);
        short h, lo;
        splitbf(cn_w2[k * 64 + n], h, lo);
        wblob[OFF_C2TH + idx] = h; wblob[OFF_C2TL + idx] = lo;
        splitbf(bn_w2[k * 64 + n], h, lo);
        wblob[OFF_B2TH + idx] = h; wblob[OFF_B2TL + idx] = lo;
    }
    if (tid < 128) {
        const int c = tid >> 6, n = tid & 63;
        float s = bn_b1[n];
        for (int kk = 0; kk < 64; ++kk)
            s = fmaf(label_emb[c * 64 + kk], bn_w1[(128 + kk) * 64 + n], s);
        contrib[c * 64 + n] = s;
    }
}

// ---------------------------------------------------------------------------
// Embedding (fp32 vector). Writes e as bf16 hi/lo planes in sigma order.
// ---------------------------------------------------------------------------
__global__ __launch_bounds__(256, 4) void emb_kernel(
    const int* __restrict__ x, const float* __restrict__ y,
    const float* __restrict__ w1, const float* __restrict__ b1,
    const float* __restrict__ w2, const float* __restrict__ b2,
    short* __restrict__ e_hi, short* __restrict__ e_lo, int* __restrict__ v_out)
{
    __shared__ float h_lds[128 * PSTR];
    const int tid = threadIdx.x;
    const int s   = tid & 7;
    const int g   = tid >> 3;
    const int jj0 = s * 8;
    const int i0  = (blockIdx.x * 32 + g) * 4;

    {
        f4 wa0 = LD4(w1 + jj0),      wa1 = LD4(w1 + jj0 + 4);
        f4 wb0 = LD4(w1 + D_ + jj0), wb1 = LD4(w1 + D_ + jj0 + 4);
        f4 bb0 = LD4(b1 + jj0),      bb1 = LD4(b1 + jj0 + 4);
#pragma unroll
        for (int pp = 0; pp < 4; ++pp) {
            const float2 yv = *(const float2*)(y + 2 * (i0 + pp));
            f4 h0, h1;
            h0.x = fmaxf(fmaf(yv.y, wb0.x, fmaf(yv.x, wa0.x, bb0.x)), 0.f);
            h0.y = fmaxf(fmaf(yv.y, wb0.y, fmaf(yv.x, wa0.y, bb0.y)), 0.f);
            h0.z = fmaxf(fmaf(yv.y, wb0.z, fmaf(yv.x, wa0.z, bb0.z)), 0.f);
            h0.w = fmaxf(fmaf(yv.y, wb0.w, fmaf(yv.x, wa0.w, bb0.w)), 0.f);
            h1.x = fmaxf(fmaf(yv.y, wb1.x, fmaf(yv.x, wa1.x, bb1.x)), 0.f);
            h1.y = fmaxf(fmaf(yv.y, wb1.y, fmaf(yv.x, wa1.y, bb1.y)), 0.f);
            h1.z = fmaxf(fmaf(yv.y, wb1.z, fmaf(yv.x, wa1.z, bb1.z)), 0.f);
            h1.w = fmaxf(fmaf(yv.y, wb1.w, fmaf(yv.x, wa1.w, bb1.w)), 0.f);
            float* hp = h_lds + (g * 4 + pp) * PSTR + jj0;
            *(f4*)hp = h0; *(f4*)(hp + 4) = h1;
        }
    }
    __syncthreads();

    float o[4][8];
    {
        f4 b20 = LD4(b2 + jj0), b21 = LD4(b2 + jj0 + 4);
#pragma unroll
        for (int pp = 0; pp < 4; ++pp) {
            o[pp][0]=b20.x; o[pp][1]=b20.y; o[pp][2]=b20.z; o[pp][3]=b20.w;
            o[pp][4]=b21.x; o[pp][5]=b21.y; o[pp][6]=b21.z; o[pp][7]=b21.w;
        }
    }
#pragma unroll 2
    for (int k4 = 0; k4 < 16; ++k4) {
        const f4 x0 = LD4(h_lds + (g * 4 + 0) * PSTR + 4 * k4);
        const f4 x1 = LD4(h_lds + (g * 4 + 1) * PSTR + 4 * k4);
        const f4 x2 = LD4(h_lds + (g * 4 + 2) * PSTR + 4 * k4);
        const f4 x3 = LD4(h_lds + (g * 4 + 3) * PSTR + 4 * k4);
        const float* wk = w2 + (4 * k4) * D_ + jj0;
#pragma unroll
        for (int q = 0; q < 4; ++q) {
            const f4 wa = LD4(wk + q * D_), wb = LD4(wk + q * D_ + 4);
            fma8(o[0], f4c(x0, q), wa, wb);
            fma8(o[1], f4c(x1, q), wa, wb);
            fma8(o[2], f4c(x2, q), wa, wb);
            fma8(o[3], f4c(x3, q), wa, wb);
        }
    }

    const int sp0 = (((jj0 >> 2) & 3) << 4) | (((jj0 >> 4) & 3) << 2);
    const int sp1 = ((((jj0 + 4) >> 2) & 3) << 4) | ((((jj0 + 4) >> 4) & 3) << 2);
#pragma unroll
    for (int pp = 0; pp < 4; ++pp) {
        const size_t rb = (size_t)(i0 + pp) * D_;
        union { short s[8]; uint2 v[2]; } uh, ul;
#pragma unroll
        for (int q = 0; q < 8; ++q) splitbf(o[pp][q], uh.s[q], ul.s[q]);
        *(uint2*)(e_hi + rb + sp0) = uh.v[0];
        *(uint2*)(e_hi + rb + sp1) = uh.v[1];
        *(uint2*)(e_lo + rb + sp0) = ul.v[0];
        *(uint2*)(e_lo + rb + sp1) = ul.v[1];
    }
    if (s < 4) v_out[i0 + s] = x[i0 + s];
}

// ---------------------------------------------------------------------------
// Global tree stage (t = 0..4): weights in LDS; swapped-operand MFMA.
// ---------------------------------------------------------------------------
__global__ __launch_bounds__(512, 2) void stage_kernel(
    const short* __restrict__ e_hi, const short* __restrict__ e_lo,
    const int* __restrict__ v_in,
    short* __restrict__ eo_hi, short* __restrict__ eo_lo, int* __restrict__ v_out,
    const short* __restrict__ wblob,
    const float* __restrict__ cn_b1, const float* __restrict__ cn_b2,
    const float* __restrict__ bn_b2, const float* __restrict__ contrib,
    const float* __restrict__ llr_w, const float* __restrict__ llr_b,
    float* __restrict__ loss_out, float2* __restrict__ pscr,
    int t, int log2Lh)
{
    __shared__ short wlds[WBLOB_SHORTS];   // 96 KB
    const int tid = threadIdx.x;
    {
        const uint4* src = (const uint4*)wblob;
        uint4* dst = (uint4*)wlds;
#pragma unroll
        for (int i = 0; i < 12; ++i)
            dst[tid + i * 512] = src[tid + i * 512];
    }
    __syncthreads();

    const int lane = tid & 63;
    const int pr = lane & 15, kg = lane >> 4;
    const int wid = tid >> 6;
    const int P0 = (blockIdx.x * 8 + wid) * 32;
    const int b  = P0 >> 11;
    const int Lh = 1 << log2Lh;

    int v1s[2], vx[2];
#pragma unroll
    for (int s = 0; s < 2; ++s) {
        const int gp = P0 + s * 16 + pr;
        const int2 vv = *(const int2*)(v_in + 2 * gp);
        v1s[s] = vv.y; vx[s] = (vv.x ^ vv.y) & 1;
    }

    f32x4 aC[2][4], aB[2][4];
#pragma unroll
    for (int mt = 0; mt < 4; ++mt) {
        const f4 bc = LD4(cn_b1 + mt * 16 + kg * 4);
#pragma unroll
        for (int s = 0; s < 2; ++s) {
            aC[s][mt] = (f32x4){bc.x, bc.y, bc.z, bc.w};
            const f4 cb = LD4(contrib + vx[s] * 64 + mt * 16 + kg * 4);
            aB[s][mt] = (f32x4){cb.x, cb.y, cb.z, cb.w};
        }
    }

#pragma unroll
    for (int kt = 0; kt < 4; ++kt) {
        short8 Eh[2], El[2];
#pragma unroll
        for (int s = 0; s < 2; ++s) {
            const size_t pos = (size_t)(2 * (P0 + s * 16 + pr) + (kt >> 1));
            const int off = (kt & 1) * 32 + kg * 8;
            Eh[s] = *(const short8*)(e_hi + pos * D_ + off);
            El[s] = *(const short8*)(e_lo + pos * D_ + off);
        }
#pragma unroll
        for (int mt = 0; mt < 4; ++mt) {
            const int fo = ((kt * 4 + mt) * 64 + lane) * 8;
            const short8 wh = *(const short8*)(wlds + OFF_C1H + fo);
            const short8 wl = *(const short8*)(wlds + OFF_C1L + fo);
            const short8 uh = *(const short8*)(wlds + OFF_B1H + fo);
            const short8 ul = *(const short8*)(wlds + OFF_B1L + fo);
#pragma unroll
            for (int s = 0; s < 2; ++s) {
                aC[s][mt] = MFMA(wh, Eh[s], aC[s][mt]);
                aC[s][mt] = MFMA(wl, Eh[s], aC[s][mt]);
                aC[s][mt] = MFMA(wh, El[s], aC[s][mt]);
                aB[s][mt] = MFMA(uh, Eh[s], aB[s][mt]);
                aB[s][mt] = MFMA(ul, Eh[s], aB[s][mt]);
                aB[s][mt] = MFMA(uh, El[s], aB[s][mt]);
            }
        }
    }

#pragma unroll
    for (int net = 0; net < 2; ++net) {
        const int w2h_off = net ? OFF_B2TH : OFF_C2TH;
        const int w2l_off = net ? OFF_B2TL : OFF_C2TL;
        const float* __restrict__ b2 = net ? bn_b2 : cn_b2;

        s4b hh[2][4], hl[2][4];
#pragma unroll
        for (int s = 0; s < 2; ++s)
#pragma unroll
            for (int ks = 0; ks < 4; ++ks) {
                const f32x4 a = net ? aB[s][ks] : aC[s][ks];
#pragma unroll
                for (int e2 = 0; e2 < 4; ++e2) {
                    short sh, sl2;
                    splitbf(fmaxf(a[e2], 0.f), sh, sl2);
                    hh[s][ks][e2] = sh; hl[s][ks][e2] = sl2;
                }
            }

        f32x4 o[2][4];
#pragma unroll
        for (int mt2 = 0; mt2 < 4; ++mt2) {
            const f4 bb = LD4(b2 + mt2 * 16 + kg * 4);
#pragma unroll
            for (int s = 0; s < 2; ++s) o[s][mt2] = (f32x4){bb.x, bb.y, bb.z, bb.w};
        }
#pragma unroll
        for (int ks = 0; ks < 4; ++ks)
#pragma unroll
            for (int mt2 = 0; mt2 < 4; ++mt2) {
                const int fo4 = ((ks * 4 + mt2) * 64 + lane) * 4;
                const s4b wh = *(const s4b*)(wlds + w2h_off + fo4);
                const s4b wl = *(const s4b*)(wlds + w2l_off + fo4);
#pragma unroll
                for (int s = 0; s < 2; ++s) {
                    o[s][mt2] = MFMA16(wh, hh[s][ks], o[s][mt2]);
                    o[s][mt2] = MFMA16(wl, hh[s][ks], o[s][mt2]);
                    o[s][mt2] = MFMA16(wh, hl[s][ks], o[s][mt2]);
                }
            }

#pragma unroll
        for (int s = 0; s < 2; ++s) {
            const int gp = P0 + s * 16 + pr;
            const int P  = gp & 2047;
            const int j  = P & (Lh - 1);
            const int io = 2 * P - j + (net ? Lh : 0);
            const int gout = b * N_ + io;

            float z0 = 0.f, z1 = 0.f;
#pragma unroll
            for (int mt2 = 0; mt2 < 4; ++mt2) {
                const int f0 = mt2 * 16 + kg * 4;
                const f4 wA = LD4(llr_w + 2 * f0);
                const f4 wB = LD4(llr_w + 2 * f0 + 4);
                z0 += o[s][mt2][0] * wA.x + o[s][mt2][1] * wA.z +
                      o[s][mt2][2] * wB.x + o[s][mt2][3] * wB.z;
                z1 += o[s][mt2][0] * wA.y + o[s][mt2][1] * wA.w +
                      o[s][mt2][2] * wB.y + o[s][mt2][3] * wB.w;
            }
            z0 += __shfl_xor(z0, 16); z1 += __shfl_xor(z1, 16);
            z0 += __shfl_xor(z0, 32); z1 += __shfl_xor(z1, 32);

            union { short sv[16]; uint4 v[2]; } ph, pl;
#pragma unroll
            for (int mt2 = 0; mt2 < 4; ++mt2)
#pragma unroll
                for (int e2 = 0; e2 < 4; ++e2) {
                    short sh, sl2;
                    splitbf(o[s][mt2][e2], sh, sl2);
                    ph.sv[mt2 * 4 + e2] = sh; pl.sv[mt2 * 4 + e2] = sl2;
                }
            const size_t eb = (size_t)gout * D_ + kg * 16;
            *(uint4*)(eo_hi + eb)     = ph.v[0];
            *(uint4*)(eo_hi + eb + 8) = ph.v[1];
            *(uint4*)(eo_lo + eb)     = pl.v[0];
            *(uint4*)(eo_lo + eb + 8) = pl.v[1];

            if (kg == 0) {
                v_out[gout] = net ? v1s[s] : vx[s];
                const float zz0 = z0 + llr_b[0], zz1 = z1 + llr_b[1];
                const float m   = fmaxf(zz0, zz1);
                const float ex0 = expf(zz0 - m), ex1 = expf(zz1 - m);
                const float inv = 1.0f / (ex0 + ex1);
                const float p0s = ex0 * inv, p1s = ex1 * inv;
                const float c0  = fminf(fmaxf(p0s, EPS_), 1.0f - EPS_);
                const float c1  = fminf(fmaxf(p1s, EPS_), 1.0f - EPS_);
                const int   lab = net ? (v1s[s] & 1) : vx[s];
                const float loss = -logf(lab ? c1 : c0);
                loss_out[(b * T_ + t) * N_ + io] = loss;
                pscr[(size_t)(b * T_ + t) * N_ + io] = make_float2(p0s, p1s);
            }
        }
    }
}

// ---------------------------------------------------------------------------
// Fused tail (t = 5..11): weights (96KB) + 128-row e-chunk in LDS.
// 1024 blocks x 512 threads: waves 0-3 = cn net, waves 4-7 = bn net
// (independent given e,v) -> per-wave chain halves, 2 waves/SIMD.
// ---------------------------------------------------------------------------
__global__ __launch_bounds__(512, 1) void fused_tail(
    const short* __restrict__ e_hi, const short* __restrict__ e_lo,
    const int* __restrict__ v_in,
    const short* __restrict__ wblob,
    const float* __restrict__ cn_b1, const float* __restrict__ cn_b2,
    const float* __restrict__ bn_b2, const float* __restrict__ contrib,
    const float* __restrict__ llr_w, const float* __restrict__ llr_b,
    float* __restrict__ loss_out, float2* __restrict__ pscr)
{
    __shared__ short wlds[WBLOB_SHORTS];       // 96 KB
    __shared__ unsigned e_lds[128 * ESTR];     // 36864 B, packed hi|lo<<16
    __shared__ int v_lds[128];
    const int tid = threadIdx.x;
    {
        const uint4* src = (const uint4*)wblob;
        uint4* dst = (uint4*)wlds;
#pragma unroll
        for (int i = 0; i < 12; ++i)
            dst[tid + i * 512] = src[tid + i * 512];
    }
    const int b = blockIdx.x >> 5, ch = blockIdx.x & 31;
    const int base_row = b * N_ + ch * 128;
    {
        const int r = tid >> 2, seg = tid & 3;           // 4 threads/row
        const size_t g = (size_t)(base_row + r) * D_ + seg * 16;
        const short8* hp = (const short8*)(e_hi + g);
        const short8* lp = (const short8*)(e_lo + g);
        unsigned* d = &e_lds[r * ESTR + seg * 16];
#pragma unroll
        for (int q = 0; q < 2; ++q) {
            const short8 h8 = hp[q];
            const short8 l8 = lp[q];
            unsigned u[8];
#pragma unroll
            for (int j2 = 0; j2 < 8; ++j2)
                u[j2] = ((unsigned)(unsigned short)h8[j2]) |
                        (((unsigned)(unsigned short)l8[j2]) << 16);
            *(uint4*)(d + 8 * q)     = make_uint4(u[0], u[1], u[2], u[3]);
            *(uint4*)(d + 8 * q + 4) = make_uint4(u[4], u[5], u[6], u[7]);
        }
        if (tid < 128) v_lds[tid] = v_in[base_row + tid];
    }
    __syncthreads();

    const int lane = tid & 63;
    const int pr = lane & 15, kg = lane >> 4;
    const int wid = tid >> 6;
    const int net = wid >> 2;                 // 0 = cn, 1 = bn
    const int p   = (wid & 3) * 16 + pr;      // local pair 0..63

    const int w1h_off = net ? OFF_B1H : OFF_C1H;
    const int w1l_off = net ? OFF_B1L : OFF_C1L;
    const int w2h_off = net ? OFF_B2TH : OFF_C2TH;
    const int w2l_off = net ? OFF_B2TL : OFF_C2TL;
    const float* __restrict__ b2 = net ? bn_b2 : cn_b2;

    int Lh = 64;
#pragma unroll 1
    for (int t = 5; t < 12; ++t, Lh >>= 1) {
        const int v0 = v_lds[2 * p], v1 = v_lds[2 * p + 1];
        const int vx = (v0 ^ v1) & 1;

        // ---- layer 1 ----
        f32x4 acc[4];
#pragma unroll
        for (int mt = 0; mt < 4; ++mt) {
            if (net) {
                const f4 cb = LD4(contrib + vx * 64 + mt * 16 + kg * 4);
                acc[mt] = (f32x4){cb.x, cb.y, cb.z, cb.w};
            } else {
                const f4 bc = LD4(cn_b1 + mt * 16 + kg * 4);
                acc[mt] = (f32x4){bc.x, bc.y, bc.z, bc.w};
            }
        }

#pragma unroll
        for (int kt = 0; kt < 4; ++kt) {
            const unsigned* src = &e_lds[(2 * p + (kt >> 1)) * ESTR + (kt & 1) * 32 + kg * 8];
            unsigned xx[8];
            *(uint4*)&xx[0] = *(const uint4*)src;
            *(uint4*)&xx[4] = *(const uint4*)(src + 4);
            union { short8 v; unsigned u[4]; } H, L;
#pragma unroll
            for (int j2 = 0; j2 < 4; ++j2) {
                H.u[j2] = (xx[2 * j2] & 0xffffu) | (xx[2 * j2 + 1] << 16);
                L.u[j2] = (xx[2 * j2] >> 16) | (xx[2 * j2 + 1] & 0xffff0000u);
            }
            const short8 Eh = H.v, El = L.v;
#pragma unroll
            for (int mt = 0; mt < 4; ++mt) {
                const int fo = ((kt * 4 + mt) * 64 + lane) * 8;
                const short8 wh = *(const short8*)(wlds + w1h_off + fo);
                const short8 wl = *(const short8*)(wlds + w1l_off + fo);
                acc[mt] = MFMA(wh, Eh, acc[mt]);
                acc[mt] = MFMA(wl, Eh, acc[mt]);
                acc[mt] = MFMA(wh, El, acc[mt]);
            }
        }

        // ---- relu + split (lane-local 16x16x16 B-frags) ----
        s4b hh[4], hl[4];
#pragma unroll
        for (int ks = 0; ks < 4; ++ks) {
#pragma unroll
            for (int e2 = 0; e2 < 4; ++e2) {
                short sh, sl2;
                splitbf(fmaxf(acc[ks][e2], 0.f), sh, sl2);
                hh[ks][e2] = sh; hl[ks][e2] = sl2;
            }
        }

        // ---- layer 2 ----
        f32x4 o[4];
#pragma unroll
        for (int mt2 = 0; mt2 < 4; ++mt2) {
            const f4 bb = LD4(b2 + mt2 * 16 + kg * 4);
            o[mt2] = (f32x4){bb.x, bb.y, bb.z, bb.w};
        }
#pragma unroll
        for (int ks = 0; ks < 4; ++ks)
#pragma unroll
            for (int mt2 = 0; mt2 < 4; ++mt2) {
                const int fo4 = ((ks * 4 + mt2) * 64 + lane) * 4;
                const s4b wh = *(const s4b*)(wlds + w2h_off + fo4);
                const s4b wl = *(const s4b*)(wlds + w2l_off + fo4);
                o[mt2] = MFMA16(wh, hh[ks], o[mt2]);
                o[mt2] = MFMA16(wl, hh[ks], o[mt2]);
                o[mt2] = MFMA16(wh, hl[ks], o[mt2]);
            }

        // ---- epilogue ----
        const int j = p & (Lh - 1);
        const int iol = 2 * p - j + (net ? Lh : 0);
        const int vnew = net ? v1 : vx;

        uint4 pk[4];
        float z0 = 0.f, z1 = 0.f;
#pragma unroll
        for (int mt2 = 0; mt2 < 4; ++mt2) {
            short qh[4], ql[4];
#pragma unroll
            for (int e2 = 0; e2 < 4; ++e2)
                splitbf(o[mt2][e2], qh[e2], ql[e2]);
            pk[mt2] = make_uint4(
                ((unsigned)(unsigned short)qh[0]) | (((unsigned)(unsigned short)ql[0]) << 16),
                ((unsigned)(unsigned short)qh[1]) | (((unsigned)(unsigned short)ql[1]) << 16),
                ((unsigned)(unsigned short)qh[2]) | (((unsigned)(unsigned short)ql[2]) << 16),
                ((unsigned)(unsigned short)qh[3]) | (((unsigned)(unsigned short)ql[3]) << 16));
            const int f0 = mt2 * 16 + kg * 4;
            const f4 wA = LD4(llr_w + 2 * f0);
            const f4 wB = LD4(llr_w + 2 * f0 + 4);
            z0 += o[mt2][0] * wA.x + o[mt2][1] * wA.z +
                  o[mt2][2] * wB.x + o[mt2][3] * wB.z;
            z1 += o[mt2][0] * wA.y + o[mt2][1] * wA.w +
                  o[mt2][2] * wB.y + o[mt2][3] * wB.w;
        }
        z0 += __shfl_xor(z0, 16); z1 += __shfl_xor(z1, 16);
        z0 += __shfl_xor(z0, 32); z1 += __shfl_xor(z1, 32);

        if (kg == 0) {
            const int io = ch * 128 + iol;
            const float zz0 = z0 + llr_b[0], zz1 = z1 + llr_b[1];
            const float m   = fmaxf(zz0, zz1);
            const float ex0 = expf(zz0 - m), ex1 = expf(zz1 - m);
            const float inv = 1.0f / (ex0 + ex1);
            const float p0s = ex0 * inv, p1s = ex1 * inv;
            const float c0  = fminf(fmaxf(p0s, EPS_), 1.0f - EPS_);
            const float c1  = fminf(fmaxf(p1s, EPS_), 1.0f - EPS_);
            const int   lab = net ? (v1 & 1) : vx;
            const float loss = -logf(lab ? c1 : c0);
            loss_out[(b * T_ + t) * N_ + io] = loss;
            pscr[(size_t)(b * T_ + t) * N_ + io] = make_float2(p0s, p1s);
        }
        __syncthreads();   // all e_lds/v_lds reads done

        {
            unsigned* d = &e_lds[iol * ESTR + kg * 16];
            *(uint4*)d        = pk[0];
            *(uint4*)(d + 4)  = pk[1];
            *(uint4*)(d + 8)  = pk[2];
            *(uint4*)(d + 12) = pk[3];
            if (kg == 0) v_lds[iol] = vnew;
        }
        __syncthreads();   // writes visible for next stage
    }
}

// ---------------------------------------------------------------------------
// Final: transpose pscr [b][t][io](2) -> pred [b][io][t][2], both copies.
// ---------------------------------------------------------------------------
__global__ __launch_bounds__(256) void pred_epilogue(
    const float2* __restrict__ pscr,
    float* __restrict__ pred1, float* __restrict__ pred2)
{
    const int idx = blockIdx.x * 256 + threadIdx.x;   // b*N + io
    const int b = idx >> 12, io = idx & (N_ - 1);
    float2 v[T_];
#pragma unroll
    for (int t = 0; t < T_; ++t)
        v[t] = pscr[(size_t)(b * T_ + t) * N_ + io];
    float* d1 = pred1 + (size_t)idx * (T_ * 2);
    float* d2 = pred2 + (size_t)idx * (T_ * 2);
#pragma unroll
    for (int q = 0; q < 6; ++q) {
        const f4 w = make_float4(v[2 * q].x, v[2 * q].y, v[2 * q + 1].x, v[2 * q + 1].y);
        *(f4*)(d1 + 4 * q) = w;
        *(f4*)(d2 + 4 * q) = w;
    }
}

// ---------------------------------------------------------------------------
extern "C" void kernel_launch(void* const* d_in, const int* in_sizes, int n_in,
                              void* d_out, int out_size, void* d_ws, size_t ws_size,
                              hipStream_t stream)
{
    const int*   x      = (const int*)  d_in[0];
    const float* y      = (const float*)d_in[1];
    const float* emb_w1 = (const float*)d_in[2];
    const float* emb_b1 = (const float*)d_in[3];
    const float* emb_w2 = (const float*)d_in[4];
    const float* emb_b2 = (const float*)d_in[5];
    const float* cn_w1  = (const float*)d_in[6];
    const float* cn_b1  = (const float*)d_in[7];
    const float* cn_w2  = (const float*)d_in[8];
    const float* cn_b2  = (const float*)d_in[9];
    const float* bn_w1  = (const float*)d_in[10];
    const float* bn_b1  = (const float*)d_in[11];
    const float* bn_w2  = (const float*)d_in[12];
    const float* bn_b2  = (const float*)d_in[13];
    const float* llr_w  = (const float*)d_in[14];
    const float* llr_b  = (const float*)d_in[15];
    const float* label_emb = (const float*)d_in[16];

    float* out      = (float*)d_out;
    float* loss_out = out;
    float* pred1    = out + (size_t)B_ * T_ * N_;
    float* pred2    = pred1 + (size_t)B_ * N_ * T_ * 2;

    const size_t EPLANE = (size_t)B_ * N_ * D_;
    short* eh_a = (short*)d_ws;
    short* el_a = eh_a + EPLANE;
    short* eh_b = el_a + EPLANE;
    short* el_b = eh_b + EPLANE;
    int*   v_a  = (int*)(el_b + EPLANE);
    int*   v_b  = v_a + B_ * N_;
    float2* pscr = (float2*)(v_b + B_ * N_);
    short* wblob = (short*)(pscr + (size_t)B_ * T_ * N_);
    float* contrib = (float*)(wblob + WBLOB_SHORTS);

    prep_kernel<<<1, 256, 0, stream>>>(
        cn_w1, cn_w2, bn_w1, bn_w2, bn_b1, label_emb, wblob, contrib);

    emb_kernel<<<dim3(B_ * N_ / 128), dim3(256), 0, stream>>>(
        x, y, emb_w1, emb_b1, emb_w2, emb_b2, eh_a, el_a, v_a);

    short* ehc = eh_a; short* elc = el_a; short* ehn = eh_b; short* eln = el_b;
    int* vc = v_a; int* vn = v_b;
    for (int t = 0; t < 5; ++t) {
        stage_kernel<<<dim3(B_ * N_ / 2 / 256), dim3(512), 0, stream>>>(
            ehc, elc, vc, ehn, eln, vn, wblob,
            cn_b1, cn_b2, bn_b2, contrib, llr_w, llr_b,
            loss_out, pscr, t, 11 - t);
        short* t1 = ehc; ehc = ehn; ehn = t1;
        short* t2 = elc; elc = eln; eln = t2;
        int* t3 = vc; vc = vn; vn = t3;
    }

    fused_tail<<<dim3(1024), dim3(512), 0, stream>>>(
        ehc, elc, vc, wblob,
        cn_b1, cn_b2, bn_b2, contrib, llr_w, llr_b,
        loss_out, pscr);

    pred_epilogue<<<dim3(B_ * N_ / 256), dim3(256), 0, stream>>>(
        pscr, pred1, pred2);
}